// Round 1
// baseline (1958.960 us; speedup 1.0000x reference)
//
#include <hip/hip_runtime.h>
#include <cstdint>
#include <cstddef>

// ---------------------------------------------------------------------------
// VQ-VAE forward on MI355X, fp32 correctness-first implementation.
//   encoder: 4x conv(k4,s2,p1)+BN+ReLU (last conv raw)  -> z [32,64,16,16]
//   VQ: dist GEMM (8192x8192x64), argmin codes, softmax stats, losses
//   decoder: 4x convT(k4,s2,p1)+BN+ReLU (last: sigmoid + recon loss)
// All fp32 vector-ALU; dist matrix materialized in ws in 2 row-chunks
// (reuses the dead h1 region).
// ---------------------------------------------------------------------------

#define DEVI __device__ __forceinline__

// ---- output layout (float32 elements, concatenated in return order) ----
#define O_RECON     0
#define O_RLOSS     2097152
#define O_CODES     2097153
#define O_ZQ        2105345
#define O_COMMIT    2629633
#define O_CB        2629634
#define O_DIV       2629635
#define O_UE        2629636
#define O_PERP      2629637
#define O_ACT       2629638

// ---- workspace layout (bytes) ----
#define WS_H1       0ull                   // 134217728 : h1 / dist-chunk / d3
#define WS_H2       134217728ull           // 33554432  : h2 / d2
#define WS_H3       167772160ull           // 16777216  : h3 / d1
#define WS_FLAT     184549376ull           // 2097152   : flat [8192][64]
#define WS_ZPART    186646528ull           // 8388608   : conv4 split-K partials
#define WS_ROWSQ    195035136ull           // 32768
#define WS_CODESQ   (WS_ROWSQ  + 32768ull)
#define WS_ROWZI    (WS_CODESQ + 32768ull) // 1/Z per row
#define WS_AVGS     (WS_ROWZI  + 32768ull)
#define WS_RMP      (WS_AVGS   + 32768ull) // u64 packed (distbits<<32|code)
#define WS_CNT      (WS_RMP    + 65536ull)
#define WS_LOSS     (WS_CNT    + 32768ull) // [0]=recon sse, [1]=commit sse

#define PART_STRIDE 524288                 // elements per conv4 cin-group

DEVI float wred64(float v){
  #pragma unroll
  for (int off=32; off>0; off>>=1) v += __shfl_down(v, off, 64);
  return v;
}
DEVI float wred32(float v){
  #pragma unroll
  for (int off=16; off>0; off>>=1) v += __shfl_down(v, off, 32);
  return v;
}

// ---------------------------------------------------------------------------
__global__ __launch_bounds__(256) void k_init(float* __restrict__ avgs,
                                              unsigned int* __restrict__ cnt,
                                              unsigned long long* __restrict__ rmp,
                                              float* __restrict__ loss)
{
  int i = blockIdx.x*256 + threadIdx.x;
  if (i < 8192){ avgs[i]=0.f; cnt[i]=0u; rmp[i]=0xFFFFFFFFFFFFFFFFull; }
  if (i < 8) loss[i]=0.f;
}

// ---------------------------------------------------------------------------
// Direct conv k=4 s=2 p=1.  16x16 output tile, OCB output channels / block.
// grid = nCing * 32 * nT*nT * nOcg.   FUSE: out = relu(acc*scale+shift)
// else: raw partial written at out + cing*partStride (split-K).
// thread: og=tid>>5 owns TOC ocs; spg=tid&31 -> (sy=spg>>1, x0=(spg&1)*8),
// i.e. 8 consecutive x on one output row.
// ---------------------------------------------------------------------------
template<int CIN_SUB, int NST, int OCB, bool FUSE>
__global__ __launch_bounds__(256)
void conv_s2(const float* __restrict__ in, const float* __restrict__ w,
             const float* __restrict__ cb_, const float* __restrict__ bns,
             const float* __restrict__ bnb, float* __restrict__ out,
             int Cin, int OC, int inH, int outH, int nT, int nOcg, int partStride)
{
  constexpr int TOC = OCB/8;
  __shared__ __align__(16) float sIn[NST][34][36];
  __shared__ __align__(16) float sW[OCB][NST][16];

  int b = blockIdx.x;
  int ocg = b % nOcg; b /= nOcg;
  int t = b % (nT*nT); b /= (nT*nT);
  int n = b % 32; b /= 32;
  int cing = b;
  int ty = t / nT, tx = t % nT;
  int oy0 = ty*16, ox0 = tx*16;
  int iy0 = 2*oy0 - 1, ix0 = 2*ox0 - 1;
  int oc0 = ocg*OCB;
  int cin0 = cing*CIN_SUB;
  int tid = threadIdx.x;
  int spg = tid & 31, og = tid >> 5;
  int sy = spg >> 1, x0 = (spg & 1)*8;

  float acc[TOC][8];
  #pragma unroll
  for (int j=0;j<TOC;j++)
    #pragma unroll
    for (int xi=0;xi<8;xi++) acc[j][xi]=0.f;

  const float* inBase = in + (size_t)n*Cin*inH*inH;

  for (int cb = 0; cb < CIN_SUB; cb += NST){
    for (int e = tid; e < NST*34*34; e += 256){
      int s = e / (34*34); int rr = (e/34)%34; int cc = e%34;
      int iy = iy0 + rr, ix = ix0 + cc;
      float v = 0.f;
      if ((unsigned)iy < (unsigned)inH && (unsigned)ix < (unsigned)inH)
        v = inBase[(size_t)(cin0+cb+s)*inH*inH + iy*inH + ix];
      sIn[s][rr][cc] = v;
    }
    for (int e = tid; e < OCB*NST; e += 256){
      int o = e / NST, s = e % NST;
      const float* wp = w + ((size_t)(oc0+o)*Cin + (cin0+cb+s))*16;
      float4 a = *(const float4*)(wp);
      float4 bq = *(const float4*)(wp+4);
      float4 cq = *(const float4*)(wp+8);
      float4 dq = *(const float4*)(wp+12);
      *(float4*)&sW[o][s][0]  = a;  *(float4*)&sW[o][s][4]  = bq;
      *(float4*)&sW[o][s][8]  = cq; *(float4*)&sW[o][s][12] = dq;
    }
    __syncthreads();
    #pragma unroll
    for (int s=0; s<NST; s++){
      #pragma unroll
      for (int ky=0; ky<4; ky++){
        int riy = 2*sy + ky;
        float seg[20];
        #pragma unroll
        for (int i=0;i<5;i++){
          float4 v = *(const float4*)&sIn[s][riy][2*x0 + 4*i];
          seg[4*i+0]=v.x; seg[4*i+1]=v.y; seg[4*i+2]=v.z; seg[4*i+3]=v.w;
        }
        #pragma unroll
        for (int j=0;j<TOC;j++){
          float4 w4 = *(const float4*)&sW[og*TOC+j][s][ky*4];
          #pragma unroll
          for (int xi=0; xi<8; xi++){
            acc[j][xi] = fmaf(seg[2*xi+0], w4.x,
                         fmaf(seg[2*xi+1], w4.y,
                         fmaf(seg[2*xi+2], w4.z,
                         fmaf(seg[2*xi+3], w4.w, acc[j][xi]))));
          }
        }
      }
    }
    __syncthreads();
  }

  int oy = oy0 + sy;
  #pragma unroll
  for (int j=0;j<TOC;j++){
    int oc = oc0 + og*TOC + j;
    float* op = out + (size_t)cing*partStride
                    + ((((size_t)n*OC + oc)*outH + oy)*outH + (ox0 + x0));
    float vv[8];
    if constexpr (FUSE){
      float sc = bns[oc];
      float sh = fmaf(cb_[oc], sc, bnb[oc]);
      #pragma unroll
      for (int xi=0;xi<8;xi++) vv[xi] = fmaxf(fmaf(acc[j][xi], sc, sh), 0.f);
    } else {
      #pragma unroll
      for (int xi=0;xi<8;xi++) vv[xi] = acc[j][xi];
    }
    *(float4*)op     = make_float4(vv[0],vv[1],vv[2],vv[3]);
    *(float4*)(op+4) = make_float4(vv[4],vv[5],vv[6],vv[7]);
  }
}

// ---------------------------------------------------------------------------
// conv4 split-K reduce: partials -> flat [8192][64] (+bias) and rowsq.
// block handles half an image's spatial positions; LDS transpose.
// ---------------------------------------------------------------------------
__global__ __launch_bounds__(256) void k_reduce_z(
    const float* __restrict__ part, const float* __restrict__ eb4,
    float* __restrict__ flat, float* __restrict__ rowsq)
{
  __shared__ float tile[128][65];
  int n = blockIdx.x >> 1;
  int half = blockIdx.x & 1;
  int tid = threadIdx.x;
  for (int it=0; it<32; it++){
    int e = tid + (it<<8);
    int oc = e >> 7;
    int spl = e & 127;
    const float* pp = part + ((size_t)n*64 + oc)*256 + half*128 + spl;
    float v = pp[0] + pp[PART_STRIDE] + pp[2*PART_STRIDE] + pp[3*PART_STRIDE] + eb4[oc];
    tile[spl][oc] = v;
  }
  __syncthreads();
  for (int it=0; it<32; it++){
    int e = tid + (it<<8);
    int il = e >> 6;
    int c = e & 63;
    flat[((size_t)n*256 + half*128 + il)*64 + c] = tile[il][c];
  }
  if (tid < 128){
    float s=0.f;
    #pragma unroll
    for (int c=0;c<64;c++){ float v = tile[tid][c]; s += v*v; }
    rowsq[n*256 + half*128 + tid] = s;
  }
}

__global__ __launch_bounds__(256) void k_codesq(const float* __restrict__ embed,
                                                float* __restrict__ codesq)
{
  int j = blockIdx.x*4 + (threadIdx.x>>6);
  int c = threadIdx.x & 63;
  float e = embed[(size_t)j*64 + c];
  float s = wred64(e*e);
  if (c==0) codesq[j] = s;
}

// ---------------------------------------------------------------------------
// VQ dist GEMM: 128x128 tile, K=64, writes dist chunk + packed row-min.
// dist[i][j] = rowsq[i] - 2*f.e + codesq[j]
// ---------------------------------------------------------------------------
__global__ __launch_bounds__(256) void vq_gemm(
    const float* __restrict__ flat, const float* __restrict__ embed,
    const float* __restrict__ rowsq, const float* __restrict__ codesq,
    float* __restrict__ dist, unsigned long long* __restrict__ rmp, int row_base)
{
  __shared__ __align__(16) float AsT[64][128];
  __shared__ __align__(16) float BsT[64][128];
  int cb = blockIdx.x & 63, rb = blockIdx.x >> 6;
  int rloc0 = rb*128;
  int row0 = row_base + rloc0;
  int c0 = cb*128;
  int tid = threadIdx.x;
  {
    int r = tid >> 1, kh = (tid & 1)*32;
    const float* ap = flat  + (size_t)(row0 + r)*64 + kh;
    const float* bp = embed + (size_t)(c0   + r)*64 + kh;
    #pragma unroll
    for (int i=0;i<8;i++){
      float4 a = *(const float4*)(ap + 4*i);
      AsT[kh+4*i+0][r]=a.x; AsT[kh+4*i+1][r]=a.y;
      AsT[kh+4*i+2][r]=a.z; AsT[kh+4*i+3][r]=a.w;
      float4 bv = *(const float4*)(bp + 4*i);
      BsT[kh+4*i+0][r]=bv.x; BsT[kh+4*i+1][r]=bv.y;
      BsT[kh+4*i+2][r]=bv.z; BsT[kh+4*i+3][r]=bv.w;
    }
  }
  __syncthreads();
  int txx = tid & 15, tyy = tid >> 4;
  float acc[8][8];
  #pragma unroll
  for (int i=0;i<8;i++)
    #pragma unroll
    for (int j=0;j<8;j++) acc[i][j]=0.f;
  for (int k=0;k<64;k++){
    float4 a0 = *(const float4*)&AsT[k][tyy*8];
    float4 a1 = *(const float4*)&AsT[k][tyy*8+4];
    float4 b0 = *(const float4*)&BsT[k][txx*8];
    float4 b1 = *(const float4*)&BsT[k][txx*8+4];
    float av[8] = {a0.x,a0.y,a0.z,a0.w,a1.x,a1.y,a1.z,a1.w};
    float bv[8] = {b0.x,b0.y,b0.z,b0.w,b1.x,b1.y,b1.z,b1.w};
    #pragma unroll
    for (int i=0;i<8;i++)
      #pragma unroll
      for (int j=0;j<8;j++) acc[i][j] = fmaf(av[i], bv[j], acc[i][j]);
  }
  float cq[8];
  #pragma unroll
  for (int j=0;j<8;j++) cq[j] = codesq[c0 + txx*8 + j];
  #pragma unroll
  for (int i=0;i<8;i++){
    float rq = rowsq[row0 + tyy*8 + i];
    float dv[8];
    #pragma unroll
    for (int j=0;j<8;j++) dv[j] = rq - 2.f*acc[i][j] + cq[j];
    float* dp = dist + (size_t)(rloc0 + tyy*8 + i)*8192 + c0 + txx*8;
    *(float4*)dp     = make_float4(dv[0],dv[1],dv[2],dv[3]);
    *(float4*)(dp+4) = make_float4(dv[4],dv[5],dv[6],dv[7]);
    unsigned long long u = 0xFFFFFFFFFFFFFFFFull;
    #pragma unroll
    for (int j=0;j<8;j++){
      unsigned long long pk = ((unsigned long long)__float_as_uint(dv[j]) << 32)
                              | (unsigned)(c0 + txx*8 + j);
      if (pk < u) u = pk;
    }
    #pragma unroll
    for (int off=8; off>0; off>>=1){
      unsigned long long o2 = __shfl_xor(u, off, 16);
      if (o2 < u) u = o2;
    }
    if (txx == 0) atomicMin(&rmp[row0 + tyy*8 + i], u);
  }
}

// 1/Z per row (softmax denominator with max-shift = row min dist)
__global__ __launch_bounds__(256) void vq_rowz(
    const float* __restrict__ dist, const unsigned long long* __restrict__ rmp,
    float* __restrict__ rowzi, int row_base)
{
  int rl = threadIdx.x >> 5, l = threadIdx.x & 31;
  int rloc = blockIdx.x*8 + rl;
  int row = row_base + rloc;
  float m = __uint_as_float((unsigned)(rmp[row] >> 32));
  const float* dp = dist + (size_t)rloc*8192;
  float s = 0.f;
  for (int c = l; c < 8192; c += 32) s += __expf(m - dp[c]);
  s = wred32(s);
  if (l==0) rowzi[row] = 1.f / s;
}

// avg_soft[j] += sum_i exp(m_i - d_ij) * (1/Z_i)
__global__ __launch_bounds__(256) void vq_colsum(
    const float* __restrict__ dist, const unsigned long long* __restrict__ rmp,
    const float* __restrict__ rowzi, float* __restrict__ avgs, int row_base)
{
  int j = (blockIdx.x & 31)*256 + threadIdx.x;
  int rg = blockIdx.x >> 5;
  float s = 0.f;
  for (int i = rg*512; i < rg*512 + 512; i++){
    int row = row_base + i;
    float m = __uint_as_float((unsigned)(rmp[row] >> 32));
    float zi = rowzi[row];
    s = fmaf(__expf(m - dist[(size_t)i*8192 + j]), zi, s);
  }
  atomicAdd(avgs + j, s);
}

// codes (as float), zq_grid gather, commitment SSE, code histogram
__global__ __launch_bounds__(256) void vq_post(
    const float* __restrict__ flat, const float* __restrict__ embed,
    const unsigned long long* __restrict__ rmp,
    float* __restrict__ out_codes, float* __restrict__ out_zq,
    float* __restrict__ loss, unsigned int* __restrict__ cnt)
{
  int r = blockIdx.x*4 + (threadIdx.x>>6);
  int c = threadIdx.x & 63;
  unsigned j = (unsigned)(rmp[r] & 0xFFFFFFFFull);
  float e = embed[(size_t)j*64 + c];
  float f = flat[(size_t)r*64 + c];
  int n = r>>8, rem = r&255, gy = rem>>4, gx = rem&15;
  out_zq[(((size_t)n*64 + c)*16 + gy)*16 + gx] = e;
  float d = f - e;
  float s = wred64(d*d);
  if (c==0){
    out_codes[r] = (float)j;
    atomicAdd(cnt + j, 1u);
    atomicAdd(loss + 1, s);
  }
}

// ---------------------------------------------------------------------------
// Transposed conv k=4 s=2 p=1 (2x upsample), 64 ocs/block, 16x16 out tile.
// Each output pixel has exactly 2x2 input taps; parity selects ky/kx pairs.
// ---------------------------------------------------------------------------
template<int NST>
__global__ __launch_bounds__(256)
void convT_s2(const float* __restrict__ in, const float* __restrict__ w,
              const float* __restrict__ db, const float* __restrict__ bns,
              const float* __restrict__ bnb, float* __restrict__ out,
              int Cin, int OC, int inH, int outH, int nT, int nOcg)
{
  __shared__ __align__(16) float sIn[NST][10][12];
  __shared__ __align__(16) float sW[64][NST][16];
  int b = blockIdx.x;
  int ocg = b % nOcg; b /= nOcg;
  int t = b % (nT*nT); b /= (nT*nT);
  int n = b;
  int ty = t/nT, tx = t%nT;
  int y0 = ty*16, x0g = tx*16;
  int iyb = y0/2 - 1, ixb = x0g/2 - 1;
  int oc0 = ocg*64;
  int tid = threadIdx.x, spg = tid&31, og = tid>>5;
  int sy = spg>>1, xh = (spg&1)*8;

  float acc[8][8];
  #pragma unroll
  for (int o=0;o<8;o++)
    #pragma unroll
    for (int xi=0;xi<8;xi++) acc[o][xi]=0.f;

  const float* inBase = in + (size_t)n*Cin*inH*inH;
  int p = sy & 1;
  int riy = (sy+p)>>1;
  int rix0 = xh>>1;

  for (int cb=0; cb<Cin; cb+=NST){
    for (int e=tid; e<NST*100; e+=256){
      int s=e/100, rr=(e/10)%10, cc=e%10;
      int iy=iyb+rr, ix=ixb+cc;
      float v=0.f;
      if ((unsigned)iy<(unsigned)inH && (unsigned)ix<(unsigned)inH)
        v = inBase[(size_t)(cb+s)*inH*inH + iy*inH + ix];
      sIn[s][rr][cc]=v;
    }
    for (int e=tid; e<64*NST; e+=256){
      int o=e/NST, s=e%NST;
      const float* wp = w + ((size_t)(oc0+o)*Cin + (cb+s))*16;
      float4 a = *(const float4*)(wp);
      float4 bq = *(const float4*)(wp+4);
      float4 cq = *(const float4*)(wp+8);
      float4 dq = *(const float4*)(wp+12);
      *(float4*)&sW[o][s][0]  = a;  *(float4*)&sW[o][s][4]  = bq;
      *(float4*)&sW[o][s][8]  = cq; *(float4*)&sW[o][s][12] = dq;
    }
    __syncthreads();
    #pragma unroll
    for (int s=0;s<NST;s++){
      float segA[8], segB[8];
      {
        float4 v0 = *(const float4*)&sIn[s][riy][rix0];
        float4 v1 = *(const float4*)&sIn[s][riy][rix0+4];
        segA[0]=v0.x; segA[1]=v0.y; segA[2]=v0.z; segA[3]=v0.w;
        segA[4]=v1.x; segA[5]=v1.y; segA[6]=v1.z; segA[7]=v1.w;
        float4 u0 = *(const float4*)&sIn[s][riy+1][rix0];
        float4 u1 = *(const float4*)&sIn[s][riy+1][rix0+4];
        segB[0]=u0.x; segB[1]=u0.y; segB[2]=u0.z; segB[3]=u0.w;
        segB[4]=u1.x; segB[5]=u1.y; segB[6]=u1.z; segB[7]=u1.w;
      }
      #pragma unroll
      for (int o=0;o<8;o++){
        const float* wpL = &sW[og*8+o][s][0];
        float4 wA = *(const float4*)(wpL + p*4);
        float4 wB = *(const float4*)(wpL + (p+2)*4);
        #pragma unroll
        for (int xi=0; xi<8; xi++){
          const int q = xi & 1;
          const int cc0 = (xi + q) >> 1;
          float wa0 = q ? wA.y : wA.x;
          float wa2 = q ? wA.w : wA.z;
          float wb0 = q ? wB.y : wB.x;
          float wb2 = q ? wB.w : wB.z;
          acc[o][xi] = fmaf(segA[cc0],   wa0,
                       fmaf(segA[cc0+1], wa2,
                       fmaf(segB[cc0],   wb0,
                       fmaf(segB[cc0+1], wb2, acc[o][xi]))));
        }
      }
    }
    __syncthreads();
  }

  int y = y0 + sy;
  #pragma unroll
  for (int o=0;o<8;o++){
    int oc = oc0 + og*8 + o;
    float sc = bns[oc];
    float sh = fmaf(db[oc], sc, bnb[oc]);
    float* op = out + (((size_t)n*OC + oc)*outH + y)*outH + x0g + xh;
    float vv[8];
    #pragma unroll
    for (int xi=0;xi<8;xi++) vv[xi] = fmaxf(fmaf(acc[o][xi], sc, sh), 0.f);
    *(float4*)op     = make_float4(vv[0],vv[1],vv[2],vv[3]);
    *(float4*)(op+4) = make_float4(vv[4],vv[5],vv[6],vv[7]);
  }
}

// convT4: 64->1ch, fused sigmoid + recon-loss SSE reduction
__global__ __launch_bounds__(256) void convT4_k(
    const float* __restrict__ in, const float* __restrict__ w,
    const float* __restrict__ db, const float* __restrict__ xref,
    float* __restrict__ recon, float* __restrict__ loss)
{
  __shared__ __align__(16) float sW[64][16];
  __shared__ __align__(16) float sIn[8][10][12];
  __shared__ float red[4];
  int b = blockIdx.x;
  int t = b & 255; int n = b >> 8;
  int tty = t >> 4, ttx = t & 15;
  int y0 = tty*16, x0 = ttx*16;
  int iyb = y0/2 - 1, ixb = x0/2 - 1;
  int tid = threadIdx.x;
  if (tid < 64){
    const float* wp = w + tid*16;
    *(float4*)&sW[tid][0]  = *(const float4*)(wp);
    *(float4*)&sW[tid][4]  = *(const float4*)(wp+4);
    *(float4*)&sW[tid][8]  = *(const float4*)(wp+8);
    *(float4*)&sW[tid][12] = *(const float4*)(wp+12);
  }
  int sy = tid >> 4, sx = tid & 15;
  int p = sy & 1, q = sx & 1;
  int riy = (sy+p)>>1, rix = (sx+q)>>1;
  float acc = 0.f;
  const float* inBase = in + (size_t)n*64*128*128;
  for (int cb=0; cb<64; cb+=8){
    for (int e=tid; e<800; e+=256){
      int s=e/100, rr=(e/10)%10, cc=e%10;
      int iy=iyb+rr, ix=ixb+cc;
      float v=0.f;
      if ((unsigned)iy<128u && (unsigned)ix<128u)
        v = inBase[(size_t)(cb+s)*16384 + iy*128 + ix];
      sIn[s][rr][cc]=v;
    }
    __syncthreads();
    #pragma unroll
    for (int s=0;s<8;s++){
      float t00=sIn[s][riy][rix],   t01=sIn[s][riy][rix+1];
      float t10=sIn[s][riy+1][rix], t11=sIn[s][riy+1][rix+1];
      const float* wp = &sW[cb+s][0];
      acc = fmaf(t00, wp[p*4+q],
            fmaf(t01, wp[p*4+q+2],
            fmaf(t10, wp[(p+2)*4+q],
            fmaf(t11, wp[(p+2)*4+q+2], acc))));
    }
    __syncthreads();
  }
  float v = acc + db[0];
  float r = 1.f/(1.f + __expf(-v));
  int y = y0+sy, xx = x0+sx;
  size_t oi = (size_t)n*65536 + (size_t)y*256 + xx;
  recon[oi] = r;
  float d = r - xref[oi];
  float s2 = wred64(d*d);
  if ((tid & 63)==0) red[tid>>6] = s2;
  __syncthreads();
  if (tid==0) atomicAdd(loss + 0, red[0]+red[1]+red[2]+red[3]);
}

// ---------------------------------------------------------------------------
__global__ __launch_bounds__(256) void k_final(
    const float* __restrict__ avgs, const unsigned int* __restrict__ cnt,
    const float* __restrict__ cluster, const float* __restrict__ loss,
    float* __restrict__ dout)
{
  __shared__ float red[3][4];
  int tid = threadIdx.x;
  float e1=0.f, e2=0.f, ac=0.f;
  for (int j=tid; j<8192; j+=256){
    float a = avgs[j] * (1.f/8192.f);
    e1 += a * __logf(a + 1e-10f);
    float h = (float)cnt[j] * (1.f/8192.f);
    e2 += h * __logf(h + 1e-10f);
    ac += (cluster[j] > 1.f) ? 1.f : 0.f;
  }
  e1 = wred64(e1); e2 = wred64(e2); ac = wred64(ac);
  int wv = tid >> 6;
  if ((tid & 63)==0){ red[0][wv]=e1; red[1][wv]=e2; red[2][wv]=ac; }
  __syncthreads();
  if (tid==0){
    float s1 = red[0][0]+red[0][1]+red[0][2]+red[0][3];
    float s2 = red[1][0]+red[1][1]+red[1][2]+red[1][3];
    float s3 = red[2][0]+red[2][1]+red[2][2]+red[2][3];
    float ue = -s1;
    dout[O_RLOSS]  = loss[0] * (1.f/2097152.f);
    float cc = loss[1] * (1.f/524288.f);
    dout[O_COMMIT] = cc;
    dout[O_CB]     = cc;
    dout[O_DIV]    = -ue / 9.010913347279288f;
    dout[O_UE]     = ue;
    dout[O_PERP]   = __expf(-s2);
    dout[O_ACT]    = s3;
  }
}

// ---------------------------------------------------------------------------
extern "C" void kernel_launch(void* const* d_in, const int* in_sizes, int n_in,
                              void* d_out, int out_size, void* d_ws, size_t ws_size,
                              hipStream_t stream)
{
  (void)in_sizes; (void)n_in; (void)out_size; (void)ws_size;
  const float* x     = (const float*)d_in[0];
  const float* ew1   = (const float*)d_in[1];
  const float* eb1   = (const float*)d_in[2];
  const float* bn1s  = (const float*)d_in[3];
  const float* bn1b  = (const float*)d_in[4];
  const float* ew2   = (const float*)d_in[5];
  const float* eb2   = (const float*)d_in[6];
  const float* bn2s  = (const float*)d_in[7];
  const float* bn2b  = (const float*)d_in[8];
  const float* ew3   = (const float*)d_in[9];
  const float* eb3   = (const float*)d_in[10];
  const float* bn3s  = (const float*)d_in[11];
  const float* bn3b  = (const float*)d_in[12];
  const float* ew4   = (const float*)d_in[13];
  const float* eb4   = (const float*)d_in[14];
  const float* embed = (const float*)d_in[15];
  const float* clsz  = (const float*)d_in[16];
  const float* dw1   = (const float*)d_in[17];
  const float* db1   = (const float*)d_in[18];
  const float* dbn1s = (const float*)d_in[19];
  const float* dbn1b = (const float*)d_in[20];
  const float* dw2   = (const float*)d_in[21];
  const float* db2   = (const float*)d_in[22];
  const float* dbn2s = (const float*)d_in[23];
  const float* dbn2b = (const float*)d_in[24];
  const float* dw3   = (const float*)d_in[25];
  const float* db3   = (const float*)d_in[26];
  const float* dbn3s = (const float*)d_in[27];
  const float* dbn3b = (const float*)d_in[28];
  const float* dw4   = (const float*)d_in[29];
  const float* db4   = (const float*)d_in[30];

  float* out = (float*)d_out;
  uint8_t* wsb = (uint8_t*)d_ws;
  float* h1    = (float*)(wsb + WS_H1);     // also dist-chunk, d3
  float* h2    = (float*)(wsb + WS_H2);     // also d2
  float* h3    = (float*)(wsb + WS_H3);     // also d1
  float* flat  = (float*)(wsb + WS_FLAT);
  float* zpart = (float*)(wsb + WS_ZPART);
  float* rowsq = (float*)(wsb + WS_ROWSQ);
  float* codesq= (float*)(wsb + WS_CODESQ);
  float* rowzi = (float*)(wsb + WS_ROWZI);
  float* avgs  = (float*)(wsb + WS_AVGS);
  unsigned long long* rmp = (unsigned long long*)(wsb + WS_RMP);
  unsigned int* cnt = (unsigned int*)(wsb + WS_CNT);
  float* loss  = (float*)(wsb + WS_LOSS);

  dim3 B(256);

  k_init<<<32, B, 0, stream>>>(avgs, cnt, rmp, loss);

  // encoder
  conv_s2<1,1,64,true><<<2048, B, 0, stream>>>(x,  ew1, eb1, bn1s, bn1b, h1, 1,  64, 256, 128, 8, 1, 0);
  conv_s2<64,4,64,true><<<512, B, 0, stream>>>(h1, ew2, eb2, bn2s, bn2b, h2, 64, 64, 128, 64, 4, 1, 0);
  conv_s2<64,4,64,true><<<256, B, 0, stream>>>(h2, ew3, eb3, bn3s, bn3b, h3, 64, 128, 64, 32, 2, 2, 0);
  conv_s2<32,4,32,false><<<256, B, 0, stream>>>(h3, ew4, nullptr, nullptr, nullptr, zpart, 128, 64, 32, 16, 1, 2, PART_STRIDE);
  k_reduce_z<<<64, B, 0, stream>>>(zpart, eb4, flat, rowsq);
  k_codesq<<<2048, B, 0, stream>>>(embed, codesq);

  // VQ in 2 row chunks (dist reuses h1's 128MB region)
  for (int chunk = 0; chunk < 2; chunk++){
    int rb = chunk * 4096;
    vq_gemm<<<2048, B, 0, stream>>>(flat, embed, rowsq, codesq, h1, rmp, rb);
    vq_rowz<<<512, B, 0, stream>>>(h1, rmp, rowzi, rb);
    vq_colsum<<<256, B, 0, stream>>>(h1, rmp, rowzi, avgs, rb);
  }
  vq_post<<<2048, B, 0, stream>>>(flat, embed, rmp, out + O_CODES, out + O_ZQ, loss, cnt);

  // decoder (d1 reuses h3, d2 reuses h2, d3 reuses h1)
  convT_s2<8><<<256,  B, 0, stream>>>(out + O_ZQ, dw1, db1, dbn1s, dbn1b, h3, 64, 128, 16, 32, 2, 2);
  convT_s2<8><<<512,  B, 0, stream>>>(h3, dw2, db2, dbn2s, dbn2b, h2, 128, 64, 32, 64, 4, 1);
  convT_s2<8><<<2048, B, 0, stream>>>(h2, dw3, db3, dbn3s, dbn3b, h1, 64, 64, 64, 128, 8, 1);
  convT4_k<<<8192, B, 0, stream>>>(h1, dw4, db4, x, out + O_RECON, loss);

  k_final<<<1, B, 0, stream>>>(avgs, cnt, clsz, loss, out);
}

// Round 2
// 1611.880 us; speedup vs baseline: 1.2153x; 1.2153x over previous
//
#include <hip/hip_runtime.h>
#include <cstdint>
#include <cstddef>

// ---------------------------------------------------------------------------
// VQ-VAE forward, MFMA split-bf16 implementation (gfx950).
//  encoder convs: fp32 NHWC activations, 3-way-split weights+activations at
//    LDS stage time, 6 MFMA terms per K16 tile  (~fp32 accuracy for argmin)
//  decoder convTs: bf16 hi/lo NHWC activations, 2-way split, 3 MFMA terms
//  VQ: dist GEMM via MFMA (row-const dropped), dist chunked into dead A1 region
// ---------------------------------------------------------------------------

#define DEVI __device__ __forceinline__

typedef short  short8 __attribute__((ext_vector_type(8)));
typedef __bf16 bf16x8 __attribute__((ext_vector_type(8)));
typedef float  f32x16 __attribute__((ext_vector_type(16)));

DEVI f32x16 MFMA(bf16x8 a, bf16x8 b, f32x16 c){
  return __builtin_amdgcn_mfma_f32_32x32x16_bf16(a, b, c, 0, 0, 0);
}

DEVI ushort f2bf(float f){
  unsigned u = __float_as_uint(f);
  unsigned r = (u + 0x7FFFu + ((u >> 16) & 1u)) >> 16;
  return (ushort)r;
}
DEVI float bf2f(ushort h){ return __uint_as_float(((unsigned)h) << 16); }

DEVI float wred64(float v){
  #pragma unroll
  for (int off=32; off>0; off>>=1) v += __shfl_down(v, off, 64);
  return v;
}
DEVI float wred32(float v){
  #pragma unroll
  for (int off=16; off>0; off>>=1) v += __shfl_down(v, off, 32);
  return v;
}

// ---- output layout (float32 elements) ----
#define O_RECON     0
#define O_RLOSS     2097152
#define O_CODES     2097153
#define O_ZQ        2105345
#define O_COMMIT    2629633
#define O_CB        2629634
#define O_DIV       2629635
#define O_UE        2629636
#define O_PERP      2629637
#define O_ACT       2629638

// ---- workspace layout (bytes) ----
// R1: A1 fp32 [32][128][128][64] | dist chunk [4096][8192] f32 | D3 bf16 h+l
#define WS_R1       0ull                       // 134,217,728
#define WS_R2       134217728ull               // A2 fp32 [32][64][66][64] | D2 h+l   34,603,008
#define WS_R3       168820736ull               // A3 fp32 [32][32][34][128] | D1 h+l  17,825,792
#define WS_FLAT     186646528ull               // fp32 [8192][64]  2,097,152
#define WS_ZQP      188743680ull               // zqP h (1,179,648) + l
#define WS_WT       191102976ull
#define WT_E2       (WS_WT)                    // 3 x 131,072
#define WT_E3       (WT_E2 + 393216ull)        // 3 x 262,144
#define WT_E4       (WT_E3 + 786432ull)        // 3 x 262,144
#define WT_D1       (WT_E4 + 786432ull)        // 2 x 262,144
#define WT_D2       (WT_D1 + 524288ull)        // 2 x 262,144
#define WT_D3       (WT_D2 + 524288ull)        // 2 x 131,072
#define WS_W4       (WT_D3 + 262144ull)        // 4,096 fp32 [16][64]
#define WS_STATS    (WS_W4 + 4096ull)          // = 194,387,968
#define ST_RMP      (WS_STATS)                 // 65,536
#define ST_CNT      (ST_RMP + 65536ull)        // 32,768
#define ST_AVGS     (ST_CNT + 32768ull)
#define ST_ROWZI    (ST_AVGS + 32768ull)
#define ST_CODESQ   (ST_ROWZI + 32768ull)
#define ST_LOSS     (ST_CODESQ + 32768ull)     // 256 B

// ---------------------------------------------------------------------------
__global__ __launch_bounds__(256) void k_init(float* __restrict__ avgs,
                                              unsigned int* __restrict__ cnt,
                                              unsigned long long* __restrict__ rmp,
                                              float* __restrict__ loss)
{
  int i = blockIdx.x*256 + threadIdx.x;
  if (i < 8192){ avgs[i]=0.f; cnt[i]=0u; rmp[i]=0xFFFFFFFFFFFFFFFFull; }
  if (i < 8) loss[i]=0.f;
}

// weight transform+split: src OIHW fp32 -> dst [16][OC][CIN] bf16 (3- or 2-way)
__global__ __launch_bounds__(256) void k_wsplit(
    const float* __restrict__ src, ushort* __restrict__ dh,
    ushort* __restrict__ dm, ushort* __restrict__ dl,
    int OC, int CIN, int isT, int three)
{
  int i = blockIdx.x*256 + threadIdx.x;
  if (i >= 16*OC*CIN) return;
  int cin = i % CIN; int t = i / CIN; int oc = t % OC; int tap = t / OC;
  int st;
  if (isT){
    int pq = tap>>2, ab = tap&3;
    int p = pq>>1, q = pq&1, a = ab>>1, b = ab&1;
    st = (p + 2*a)*4 + (q + 2*b);
  } else st = tap;
  float v = src[((size_t)oc*CIN + cin)*16 + st];
  ushort h = f2bf(v); float r = v - bf2f(h);
  if (three){
    ushort m = f2bf(r); float r2 = r - bf2f(m);
    dm[i] = m; dl[i] = f2bf(r2);
  } else {
    dl[i] = f2bf(r);
  }
  dh[i] = h;
}

__global__ __launch_bounds__(256) void k_w4prep(const float* __restrict__ dw4,
                                                float* __restrict__ w4)
{
  int i = blockIdx.x*256 + threadIdx.x;
  if (i >= 1024) return;
  int c = i & 63; int t16 = i >> 6;
  int pq = t16 >> 2, ab = t16 & 3;
  int p = pq>>1, q = pq&1, a = ab>>1, b = ab&1;
  w4[i] = dw4[(size_t)c*16 + (p+2*a)*4 + (q+2*b)];
}

// zero the x-pad columns (col 0 and Wp-1). cwords = C*elemBytes/4.
__global__ __launch_bounds__(256) void k_zpad(unsigned* __restrict__ b0,
                                              unsigned* __restrict__ b1,
                                              int rows, int Wp, int cwords)
{
  int i = blockIdx.x*256 + threadIdx.x;
  int total = rows*2*cwords;
  if (i >= total) return;
  int pos = i / cwords, cw = i % cwords;
  int row = pos >> 1, side = pos & 1;
  size_t w = ((size_t)row*Wp + (side ? (Wp-1) : 0))*cwords + cw;
  b0[w] = 0u;
  if (b1) b1[w] = 0u;
}

// ---------------------------------------------------------------------------
// conv1: 1->64ch, k4 s2 p1, direct fp32, writes NHWC fp32 [32][128][128][64]
// ---------------------------------------------------------------------------
__global__ __launch_bounds__(256) void enc_conv1(
    const float* __restrict__ x, const float* __restrict__ w,
    const float* __restrict__ cb_, const float* __restrict__ bns,
    const float* __restrict__ bnb, float* __restrict__ out)
{
  __shared__ __align__(16) float sIn[34][36];
  __shared__ __align__(16) float sW[64][16];
  int b = blockIdx.x;
  int t = b & 63, n = b >> 6;
  int ty = t >> 3, tx = t & 7;
  int oy0 = ty*16, ox0 = tx*16;
  int iy0 = 2*oy0 - 1, ix0 = 2*ox0 - 1;
  int tid = threadIdx.x;
  int spg = tid & 31, og = tid >> 5;
  int sy = spg >> 1, x0 = (spg & 1)*8;

  if (tid < 64){
    const float* wp = w + tid*16;
    *(float4*)&sW[tid][0]  = *(const float4*)(wp);
    *(float4*)&sW[tid][4]  = *(const float4*)(wp+4);
    *(float4*)&sW[tid][8]  = *(const float4*)(wp+8);
    *(float4*)&sW[tid][12] = *(const float4*)(wp+12);
  }
  for (int e = tid; e < 34*34; e += 256){
    int rr = e/34, cc = e%34;
    int iy = iy0+rr, ix = ix0+cc;
    float v = 0.f;
    if ((unsigned)iy < 256u && (unsigned)ix < 256u)
      v = x[(size_t)n*65536 + iy*256 + ix];
    sIn[rr][cc] = v;
  }
  __syncthreads();

  float acc[8][8];
  #pragma unroll
  for (int j=0;j<8;j++)
    #pragma unroll
    for (int xi=0;xi<8;xi++) acc[j][xi]=0.f;

  #pragma unroll
  for (int ky=0; ky<4; ky++){
    int riy = 2*sy + ky;
    float seg[20];
    #pragma unroll
    for (int i=0;i<5;i++){
      float4 v = *(const float4*)&sIn[riy][2*x0 + 4*i];
      seg[4*i+0]=v.x; seg[4*i+1]=v.y; seg[4*i+2]=v.z; seg[4*i+3]=v.w;
    }
    #pragma unroll
    for (int j=0;j<8;j++){
      float4 w4v = *(const float4*)&sW[og*8+j][ky*4];
      #pragma unroll
      for (int xi=0; xi<8; xi++){
        acc[j][xi] = fmaf(seg[2*xi+0], w4v.x,
                     fmaf(seg[2*xi+1], w4v.y,
                     fmaf(seg[2*xi+2], w4v.z,
                     fmaf(seg[2*xi+3], w4v.w, acc[j][xi]))));
      }
    }
  }

  float sc[8], sh[8];
  #pragma unroll
  for (int j=0;j<8;j++){
    int oc = og*8+j;
    sc[j] = bns[oc];
    sh[j] = fmaf(cb_[oc], sc[j], bnb[oc]);
  }
  int oy = oy0 + sy;
  #pragma unroll
  for (int xi=0; xi<8; xi++){
    int oxg = ox0 + x0 + xi;
    float* op = out + (((size_t)n*128 + oy)*128 + oxg)*64 + og*8;
    float4 q0, q1;
    q0.x = fmaxf(fmaf(acc[0][xi], sc[0], sh[0]), 0.f);
    q0.y = fmaxf(fmaf(acc[1][xi], sc[1], sh[1]), 0.f);
    q0.z = fmaxf(fmaf(acc[2][xi], sc[2], sh[2]), 0.f);
    q0.w = fmaxf(fmaf(acc[3][xi], sc[3], sh[3]), 0.f);
    q1.x = fmaxf(fmaf(acc[4][xi], sc[4], sh[4]), 0.f);
    q1.y = fmaxf(fmaf(acc[5][xi], sc[5], sh[5]), 0.f);
    q1.z = fmaxf(fmaf(acc[6][xi], sc[6], sh[6]), 0.f);
    q1.w = fmaxf(fmaf(acc[7][xi], sc[7], sh[7]), 0.f);
    *(float4*)op     = q0;
    *(float4*)(op+4) = q1;
  }
}

// ---------------------------------------------------------------------------
// Encoder conv k4 s2 p1 as tap-GEMM, 3-way-split MFMA (6 terms).
// in: fp32 NHWC [32][INH][INWP][CIN]; out: fp32 NHWC padded, or flat.
// block = 256 thr (4 waves 2x2), tile M=64 x N=64, taps 16 x K=CIN.
// ---------------------------------------------------------------------------
template<int CIN, int OC, int OUTW, int OUTH, int INW, int INH, bool XPAD, bool TOFLAT>
__global__ __launch_bounds__(256) void enc_conv(
    const float* __restrict__ in,
    const ushort* __restrict__ wtH, const ushort* __restrict__ wtM,
    const ushort* __restrict__ wtL,
    const float* __restrict__ cb_, const float* __restrict__ bns,
    const float* __restrict__ bnb,
    float* __restrict__ out, int nOcg)
{
  constexpr int INWP  = XPAD ? (INW+2) : INW;
  constexpr int WP    = INW + 2;
  constexpr int NROWS = 64 / OUTW;
  constexpr int AELEM = NROWS * WP * CIN;
  constexpr int BCIN  = (CIN > 64) ? 64 : CIN;
  constexpr int BELEM = 64 * BCIN;
  constexpr int SCRSZ = (3*BELEM*2 > 64*68*4) ? 3*BELEM*2 : 64*68*4;

  __shared__ __align__(16) ushort sAh[AELEM], sAm[AELEM], sAl[AELEM];
  __shared__ __align__(16) char sScr[SCRSZ];
  ushort* sBh = (ushort*)sScr;
  ushort* sBm = sBh + BELEM;
  ushort* sBl = sBm + BELEM;
  float*  sC  = (float*)sScr;

  int b = blockIdx.x;
  int ocg = b % nOcg; b /= nOcg;
  int yb  = b % (OUTH/NROWS); b /= (OUTH/NROWS);
  int n = b;
  int oy0 = yb * NROWS, oc0 = ocg * 64;

  int tid = threadIdx.x;
  int l = tid & 63, wave = tid >> 6;
  int wm = wave >> 1, wn = wave & 1;
  int r = l & 31, kp = l >> 5;
  int idx = wm*32 + r;
  int oy_off = idx / OUTW, ox = idx % OUTW;

  f32x16 acc;
  #pragma unroll
  for (int i=0;i<16;i++) acc[i] = 0.f;

  const size_t nbase = (size_t)n * INH * INWP * CIN;

  for (int ky = 0; ky < 4; ky++){
    __syncthreads();
    // ---- stage + 3-split A rows for this ky ----
    for (int c = tid; c < AELEM/8; c += 256){
      int j  = c / (WP*CIN/8);
      int rm = c % (WP*CIN/8);
      int lx = rm / (CIN/8);
      int c8 = (rm % (CIN/8)) * 8;
      int iy = 2*(oy0 + j) - 1 + ky;
      bool ok = (unsigned)iy < (unsigned)INH;
      int gx = XPAD ? lx : (lx - 1);
      if (!XPAD) ok = ok && ((unsigned)gx < (unsigned)INW);
      float4 v0 = {0,0,0,0}, v1 = {0,0,0,0};
      if (ok){
        const float* s = in + nbase + ((size_t)iy*INWP + gx)*CIN + c8;
        v0 = *(const float4*)s; v1 = *(const float4*)(s+4);
      }
      float vv[8] = {v0.x,v0.y,v0.z,v0.w,v1.x,v1.y,v1.z,v1.w};
      short8 hh, mm, ll;
      #pragma unroll
      for (int e=0;e<8;e++){
        ushort h = f2bf(vv[e]); float r1 = vv[e] - bf2f(h);
        ushort m = f2bf(r1);    float r2 = r1 - bf2f(m);
        hh[e] = (short)h; mm[e] = (short)m; ll[e] = (short)f2bf(r2);
      }
      unsigned off = (unsigned)(((j*WP + lx)*CIN + c8)*2) ^ ((((unsigned)lx>>1)&7u)<<4);
      *(short8*)((char*)sAh + off) = hh;
      *(short8*)((char*)sAm + off) = mm;
      *(short8*)((char*)sAl + off) = ll;
    }
    for (int kx = 0; kx < 4; kx++){
      int tap = ky*4 + kx;
      for (int ch = 0; ch < CIN; ch += BCIN){
        __syncthreads();
        // ---- stage B (pre-split weights) ----
        for (int c = tid; c < BELEM/8; c += 256){
          int oc = c / (BCIN/8);
          int c8 = (c % (BCIN/8)) * 8;
          size_t s = ((size_t)tap*OC + oc0 + oc)*CIN + ch + c8;
          unsigned off = (unsigned)((oc*BCIN + c8)*2) ^ (((unsigned)oc&7u)<<4);
          *(short8*)((char*)sBh + off) = *(const short8*)(wtH + s);
          *(short8*)((char*)sBm + off) = *(const short8*)(wtM + s);
          *(short8*)((char*)sBl + off) = *(const short8*)(wtL + s);
        }
        __syncthreads();
        int lx = 2*ox + kx;
        unsigned asw  = ((((unsigned)lx>>1)&7u)<<4);
        unsigned alin = (unsigned)(((oy_off*WP + lx)*CIN)*2);
        int ocl = wn*32 + r;
        unsigned bsw  = (((unsigned)ocl&7u)<<4);
        unsigned blin = (unsigned)((ocl*BCIN)*2);
        #pragma unroll
        for (int ct = 0; ct < BCIN/16; ct++){
          unsigned kbA = (unsigned)((ch + ct*16 + kp*8)*2);
          unsigned kbB = (unsigned)((ct*16 + kp*8)*2);
          unsigned ao = (alin + kbA) ^ asw;
          unsigned bo = (blin + kbB) ^ bsw;
          bf16x8 ah = *(const bf16x8*)((char*)sAh + ao);
          bf16x8 am = *(const bf16x8*)((char*)sAm + ao);
          bf16x8 al = *(const bf16x8*)((char*)sAl + ao);
          bf16x8 bh = *(const bf16x8*)((char*)sBh + bo);
          bf16x8 bm = *(const bf16x8*)((char*)sBm + bo);
          bf16x8 bl = *(const bf16x8*)((char*)sBl + bo);
          acc = MFMA(ah, bh, acc);
          acc = MFMA(ah, bm, acc);
          acc = MFMA(am, bh, acc);
          acc = MFMA(ah, bl, acc);
          acc = MFMA(am, bm, acc);
          acc = MFMA(al, bh, acc);
        }
      }
    }
  }
  // ---- epilogue via LDS transpose ----
  __syncthreads();
  #pragma unroll
  for (int q = 0; q < 16; q++){
    int rowt = (q&3) + 8*(q>>2) + 4*kp;
    sC[(wm*32 + rowt)*68 + wn*32 + r] = acc[q];
  }
  __syncthreads();
  {
    int e = tid;
    int m = e >> 2, qq = e & 3;
    int oc = oc0 + qq*16;
    int oyg = oy0 + m / OUTW;
    int oxg = m % OUTW;
    if (TOFLAT){
      size_t row = (size_t)n*256 + oyg*16 + oxg;
      float* op = out + row*64 + qq*16;
      #pragma unroll
      for (int i=0;i<16;i+=4){
        float4 o4;
        o4.x = sC[m*68 + qq*16 + i+0] + cb_[oc+i+0];
        o4.y = sC[m*68 + qq*16 + i+1] + cb_[oc+i+1];
        o4.z = sC[m*68 + qq*16 + i+2] + cb_[oc+i+2];
        o4.w = sC[m*68 + qq*16 + i+3] + cb_[oc+i+3];
        *(float4*)(op + i) = o4;
      }
    } else {
      float* op = out + (((size_t)n*OUTH + oyg)*(OUTW+2) + oxg + 1)*OC + oc;
      #pragma unroll
      for (int i=0;i<16;i+=4){
        float4 o4; float tmp[4];
        #pragma unroll
        for (int u=0; u<4; u++){
          float s1 = bns[oc+i+u];
          float s2 = fmaf(cb_[oc+i+u], s1, bnb[oc+i+u]);
          tmp[u] = fmaxf(fmaf(sC[m*68 + qq*16 + i+u], s1, s2), 0.f);
        }
        o4.x=tmp[0]; o4.y=tmp[1]; o4.z=tmp[2]; o4.w=tmp[3];
        *(float4*)(op + i) = o4;
      }
    }
  }
}

// ---------------------------------------------------------------------------
__global__ __launch_bounds__(256) void k_codesq(const float* __restrict__ embed,
                                                float* __restrict__ codesq)
{
  int j = blockIdx.x*4 + (threadIdx.x>>6);
  int c = threadIdx.x & 63;
  float e = embed[(size_t)j*64 + c];
  float s = wred64(e*e);
  if (c==0) codesq[j] = s;
}

DEVI float rmp_minval(unsigned long long v){
  unsigned skey = (unsigned)(v >> 32);
  unsigned u = (skey & 0x80000000u) ? (skey ^ 0x80000000u) : ~skey;
  return __uint_as_float(u);
}

// ---------------------------------------------------------------------------
// VQ dist GEMM: 128x128 tile, K=64, 3-way-split MFMA (6 terms).
// dist'[i][j] = |e_j|^2 - 2 f_i.e_j   (row constant dropped; argmin/softmax inv.)
// ---------------------------------------------------------------------------
__global__ __launch_bounds__(256) void vq_gemm_mfma(
    const float* __restrict__ flat, const float* __restrict__ embed,
    const float* __restrict__ codesq, float* __restrict__ dist,
    unsigned long long* __restrict__ rmp, int row_base)
{
  __shared__ __align__(16) ushort sAh[128*64], sAm[128*64], sAl[128*64];
  __shared__ __align__(16) ushort sBh[128*64], sBm[128*64], sBl[128*64];
  int cb = blockIdx.x & 63, rb = blockIdx.x >> 6;
  int rloc0 = rb*128, row0 = row_base + rloc0, c0 = cb*128;
  int tid = threadIdx.x, l = tid&63, wave = tid>>6;
  int wm = wave>>1, wn = wave&1, r = l&31, kp = l>>5;

  for (int c = tid; c < 2048; c += 256){
    int isB = c >> 10, cc = c & 1023;
    int rr = cc >> 3, c8 = (cc & 7)*8;
    const float* s = (isB ? (embed + (size_t)(c0+rr)*64)
                          : (flat  + (size_t)(row0+rr)*64)) + c8;
    float4 v0 = *(const float4*)s, v1 = *(const float4*)(s+4);
    float vv[8] = {v0.x,v0.y,v0.z,v0.w,v1.x,v1.y,v1.z,v1.w};
    short8 hh, mm, ll;
    #pragma unroll
    for (int e=0;e<8;e++){
      ushort h = f2bf(vv[e]); float r1 = vv[e] - bf2f(h);
      ushort m = f2bf(r1);    float r2 = r1 - bf2f(m);
      hh[e]=(short)h; mm[e]=(short)m; ll[e]=(short)f2bf(r2);
    }
    unsigned off = (unsigned)((rr*64 + c8)*2) ^ (((unsigned)rr&7u)<<4);
    if (isB){
      *(short8*)((char*)sBh + off) = hh;
      *(short8*)((char*)sBm + off) = mm;
      *(short8*)((char*)sBl + off) = ll;
    } else {
      *(short8*)((char*)sAh + off) = hh;
      *(short8*)((char*)sAm + off) = mm;
      *(short8*)((char*)sAl + off) = ll;
    }
  }
  __syncthreads();

  f32x16 acc[2][2];
  #pragma unroll
  for (int mt=0;mt<2;mt++)
    #pragma unroll
    for (int nt=0;nt<2;nt++)
      #pragma unroll
      for (int i=0;i<16;i++) acc[mt][nt][i]=0.f;

  #pragma unroll
  for (int ks=0; ks<4; ks++){
    unsigned kb = (unsigned)((ks*16 + kp*8)*2);
    bf16x8 Ah[2],Am[2],Al[2],Bh[2],Bm[2],Bl[2];
    #pragma unroll
    for (int mt=0;mt<2;mt++){
      int rowi = wm*64 + mt*32 + r;
      unsigned o = ((unsigned)(rowi*128) + kb) ^ (((unsigned)rowi&7u)<<4);
      Ah[mt] = *(const bf16x8*)((char*)sAh + o);
      Am[mt] = *(const bf16x8*)((char*)sAm + o);
      Al[mt] = *(const bf16x8*)((char*)sAl + o);
    }
    #pragma unroll
    for (int nt=0;nt<2;nt++){
      int coli = wn*64 + nt*32 + r;
      unsigned o = ((unsigned)(coli*128) + kb) ^ (((unsigned)coli&7u)<<4);
      Bh[nt] = *(const bf16x8*)((char*)sBh + o);
      Bm[nt] = *(const bf16x8*)((char*)sBm + o);
      Bl[nt] = *(const bf16x8*)((char*)sBl + o);
    }
    #pragma unroll
    for (int mt=0;mt<2;mt++)
      #pragma unroll
      for (int nt=0;nt<2;nt++){
        acc[mt][nt] = MFMA(Ah[mt], Bh[nt], acc[mt][nt]);
        acc[mt][nt] = MFMA(Ah[mt], Bm[nt], acc[mt][nt]);
        acc[mt][nt] = MFMA(Am[mt], Bh[nt], acc[mt][nt]);
        acc[mt][nt] = MFMA(Ah[mt], Bl[nt], acc[mt][nt]);
        acc[mt][nt] = MFMA(Am[mt], Bm[nt], acc[mt][nt]);
        acc[mt][nt] = MFMA(Al[mt], Bh[nt], acc[mt][nt]);
      }
  }

  float cq[2];
  cq[0] = codesq[c0 + wn*64 + r];
  cq[1] = codesq[c0 + wn*64 + 32 + r];
  #pragma unroll
  for (int mt=0; mt<2; mt++){
    #pragma unroll
    for (int q=0; q<16; q++){
      int rowt = (q&3) + 8*(q>>2) + 4*kp;
      int grow = rloc0 + wm*64 + mt*32 + rowt;
      unsigned long long kmin = 0xFFFFFFFFFFFFFFFFull;
      #pragma unroll
      for (int nt=0; nt<2; nt++){
        int col = c0 + wn*64 + nt*32 + r;
        float d = cq[nt] - 2.f*acc[mt][nt][q];
        dist[(size_t)grow*8192 + col] = d;
        unsigned u = __float_as_uint(d);
        unsigned sgn = (unsigned)((int)u >> 31);
        unsigned skey = u ^ (sgn | 0x80000000u);
        unsigned long long key = (((unsigned long long)skey)<<32) | (unsigned)col;
        if (key < kmin) kmin = key;
      }
      #pragma unroll
      for (int off2=16; off2>0; off2>>=1){
        unsigned long long o2 = __shfl_xor(kmin, off2, 64);
        if (o2 < kmin) kmin = o2;
      }
      if (r == 0) atomicMin(&rmp[row_base + grow], kmin);
    }
  }
}

// 1/Z per row
__global__ __launch_bounds__(256) void vq_rowz(
    const float* __restrict__ dist, const unsigned long long* __restrict__ rmp,
    float* __restrict__ rowzi, int row_base)
{
  int rl = threadIdx.x >> 5, lane = threadIdx.x & 31;
  int rloc = blockIdx.x*8 + rl;
  int row = row_base + rloc;
  float m = rmp_minval(rmp[row]);
  const float* dp = dist + (size_t)rloc*8192;
  float s = 0.f;
  for (int c = lane; c < 8192; c += 32) s += __expf(m - dp[c]);
  s = wred32(s);
  if (lane==0) rowzi[row] = 1.f / s;
}

__global__ __launch_bounds__(256) void vq_colsum(
    const float* __restrict__ dist, const unsigned long long* __restrict__ rmp,
    const float* __restrict__ rowzi, float* __restrict__ avgs, int row_base)
{
  int j = (blockIdx.x & 31)*256 + threadIdx.x;
  int rg = blockIdx.x >> 5;
  float s = 0.f;
  for (int i = rg*512; i < rg*512 + 512; i++){
    int row = row_base + i;
    float m = rmp_minval(rmp[row]);
    float zi = rowzi[row];
    s = fmaf(__expf(m - dist[(size_t)i*8192 + j]), zi, s);
  }
  atomicAdd(avgs + j, s);
}

// codes, zq (fp32 NCHW out), zqP (bf16 hi/lo NHWC padded), commit SSE, hist
__global__ __launch_bounds__(256) void vq_post(
    const float* __restrict__ flat, const float* __restrict__ embed,
    const unsigned long long* __restrict__ rmp,
    float* __restrict__ out_codes, float* __restrict__ out_zq,
    ushort* __restrict__ zqPh, ushort* __restrict__ zqPl,
    float* __restrict__ loss, unsigned int* __restrict__ cnt)
{
  int r = blockIdx.x*4 + (threadIdx.x>>6);
  int c = threadIdx.x & 63;
  unsigned j = (unsigned)(rmp[r] & 0xFFFFFFFFull);
  float e = embed[(size_t)j*64 + c];
  float f = flat[(size_t)r*64 + c];
  int n = r>>8, rem = r&255, gy = rem>>4, gx = rem&15;
  out_zq[(((size_t)n*64 + c)*16 + gy)*16 + gx] = e;
  ushort h = f2bf(e);
  size_t pz = (((size_t)n*16 + gy)*18 + gx + 1)*64 + c;
  zqPh[pz] = h; zqPl[pz] = f2bf(e - bf2f(h));
  float d = f - e;
  float s2 = wred64(d*d);
  if (c==0){
    out_codes[r] = (float)j;
    atomicAdd(cnt + j, 1u);
    atomicAdd(loss + 1, s2);
  }
}

// ---------------------------------------------------------------------------
// Decoder convT k4 s2 p1 as parity-class tap-GEMM, 2-way-split MFMA (3 terms).
// in: bf16 hi/lo NHWC x-padded [32][SH][SW+2][CIN]; out bf16 hi/lo NHWC.
// grid: n * (SH/TR) * nOcg * 4parities, block 256.
// ---------------------------------------------------------------------------
template<int CIN, int OC, int SW, int SH, bool OUTPAD>
__global__ __launch_bounds__(256) void dec_convT(
    const ushort* __restrict__ inH, const ushort* __restrict__ inL,
    const ushort* __restrict__ wtH, const ushort* __restrict__ wtL,
    const float* __restrict__ db, const float* __restrict__ bns,
    const float* __restrict__ bnb,
    ushort* __restrict__ outH, ushort* __restrict__ outL, int nOcg)
{
  constexpr int TR    = 64 / SW;
  constexpr int NRA   = TR + 1;
  constexpr int WPin  = SW + 2;
  constexpr int AELEM = NRA * WPin * CIN;
  constexpr int BCIN  = (CIN > 64) ? 64 : CIN;
  constexpr int BELEM = 64 * BCIN;
  constexpr int OUTH  = 2*SH;
  constexpr int OW    = OUTPAD ? (2*SW+2) : (2*SW);
  constexpr int SCRSZ = (2*BELEM*2 > 64*68*4) ? 2*BELEM*2 : 64*68*4;

  __shared__ __align__(16) ushort sAh[AELEM], sAl[AELEM];
  __shared__ __align__(16) char sScr[SCRSZ];
  ushort* sBh = (ushort*)sScr;
  ushort* sBl = sBh + BELEM;
  float*  sC  = (float*)sScr;

  int b = blockIdx.x;
  int par = b & 3; b >>= 2;
  int ocg = b % nOcg; b /= nOcg;
  int tb = b % (SH/TR); b /= (SH/TR);
  int n = b;
  int p = par >> 1, q = par & 1;
  int t0 = tb * TR, oc0 = ocg * 64;

  int tid = threadIdx.x, l = tid&63, wave = tid>>6;
  int wm = wave>>1, wn = wave&1;
  int r = l&31, kp = l>>5;
  int idx = wm*32 + r;
  int t_off = idx / SW, s = idx % SW;

  f32x16 acc;
  #pragma unroll
  for (int i=0;i<16;i++) acc[i]=0.f;

  // ---- stage A rows (once) ----
  for (int c = tid; c < AELEM/8; c += 256){
    int j  = c / (WPin*CIN/8);
    int rm = c % (WPin*CIN/8);
    int lx = rm / (CIN/8);
    int c8 = (rm % (CIN/8)) * 8;
    int giy = t0 + p - 1 + j;
    bool ok = (unsigned)giy < (unsigned)SH;
    short8 vh = {0,0,0,0,0,0,0,0}, vl = {0,0,0,0,0,0,0,0};
    if (ok){
      size_t sidx = (((size_t)n*SH + giy)*WPin + lx)*CIN + c8;
      vh = *(const short8*)(inH + sidx);
      vl = *(const short8*)(inL + sidx);
    }
    unsigned off = (unsigned)(((j*WPin + lx)*CIN + c8)*2) ^ (((unsigned)lx&7u)<<4);
    *(short8*)((char*)sAh + off) = vh;
    *(short8*)((char*)sAl + off) = vl;
  }

  for (int ab = 0; ab < 4; ab++){
    int a = ab>>1, bb = ab&1;
    for (int ch = 0; ch < CIN; ch += BCIN){
      __syncthreads();
      for (int c = tid; c < BELEM/8; c += 256){
        int oc = c / (BCIN/8);
        int c8 = (c % (BCIN/8)) * 8;
        size_t sidx = ((size_t)(par*4 + ab)*OC + oc0 + oc)*CIN + ch + c8;
        unsigned off = (unsigned)((oc*BCIN + c8)*2) ^ (((unsigned)oc&7u)<<4);
        *(short8*)((char*)sBh + off) = *(const short8*)(wtH + sidx);
        *(short8*)((char*)sBl + off) = *(const short8*)(wtL + sidx);
      }
      __syncthreads();
      int lx = s + q + bb;
      int rs = t_off + a;
      unsigned asw  = (((unsigned)lx&7u)<<4);
      unsigned alin = (unsigned)(((rs*WPin + lx)*CIN)*2);
      int ocl = wn*32 + r;
      unsigned bsw  = (((unsigned)ocl&7u)<<4);
      unsigned blin = (unsigned)((ocl*BCIN)*2);
      #pragma unroll
      for (int ct = 0; ct < BCIN/16; ct++){
        unsigned kbA = (unsigned)((ch + ct*16 + kp*8)*2);
        unsigned kbB = (unsigned)((ct*16 + kp*8)*2);
        unsigned ao = (alin + kbA) ^ asw;
        unsigned bo = (blin + kbB) ^ bsw;
        bf16x8 ah = *(const bf16x8*)((char*)sAh + ao);
        bf16x8 al = *(const bf16x8*)((char*)sAl + ao);
        bf16x8 bh = *(const bf16x8*)((char*)sBh + bo);
        bf16x8 bl = *(const bf16x8*)((char*)sBl + bo);
        acc = MFMA(ah, bh, acc);
        acc = MFMA(ah, bl, acc);
        acc = MFMA(al, bh, acc);
      }
    }
  }
  __syncthreads();
  #pragma unroll
  for (int qre = 0; qre < 16; qre++){
    int rowt = (qre&3) + 8*(qre>>2) + 4*kp;
    sC[(wm*32 + rowt)*68 + wn*32 + r] = acc[qre];
  }
  __syncthreads();
  {
    int e = tid;
    int m = e >> 2, qq = e & 3;
    int oc = oc0 + qq*16;
    int y  = 2*(t0 + m/SW) + p;
    int xs = m % SW;
    int xp = OUTPAD ? (2*xs + q + 1) : (2*xs + q);
    size_t base = (((size_t)n*OUTH + y)*OW + xp)*OC + oc;
    short8 h0, h1, l0, l1;
    #pragma unroll
    for (int i=0;i<16;i++){
      float s1 = bns[oc+i];
      float s2 = fmaf(db[oc+i], s1, bnb[oc+i]);
      float v = fmaxf(fmaf(sC[m*68 + qq*16 + i], s1, s2), 0.f);
      ushort h = f2bf(v);
      ushort lo = f2bf(v - bf2f(h));
      if (i < 8){ h0[i]=(short)h; l0[i]=(short)lo; }
      else      { h1[i-8]=(short)h; l1[i-8]=(short)lo; }
    }
    *(short8*)(outH + base)     = h0;
    *(short8*)(outH + base + 8) = h1;
    *(short8*)(outL + base)     = l0;
    *(short8*)(outL + base + 8) = l1;
  }
}

// convT4: 64->1ch + sigmoid + recon-loss. One thread per output pixel.
__global__ __launch_bounds__(256) void dec_convT4(
    const ushort* __restrict__ d3H, const ushort* __restrict__ d3L,
    const float* __restrict__ w4, const float* __restrict__ db4,
    const float* __restrict__ xref, float* __restrict__ recon,
    float* __restrict__ loss)
{
  int id = blockIdx.x*256 + threadIdx.x;
  int n = id >> 16, rem = id & 65535, y = rem >> 8, x = rem & 255;
  int p = y&1, q = x&1, t = y>>1, s = x>>1;
  int par = p*2 + q;
  float acc = 0.f;
  #pragma unroll
  for (int a=0; a<2; a++){
    int row = t + p - 1 + a;
    if ((unsigned)row >= 128u) continue;
    #pragma unroll
    for (int bb=0; bb<2; bb++){
      int col = s + q - 1 + bb;
      if ((unsigned)col >= 128u) continue;
      size_t base = (((size_t)n*128 + row)*128 + col)*64;
      const float* wp = w4 + (par*4 + a*2 + bb)*64;
      #pragma unroll
      for (int c8=0; c8<64; c8+=8){
        short8 vh = *(const short8*)(d3H + base + c8);
        short8 vl = *(const short8*)(d3L + base + c8);
        float4 w0 = *(const float4*)(wp + c8);
        float4 w1 = *(const float4*)(wp + c8 + 4);
        float wv[8] = {w0.x,w0.y,w0.z,w0.w,w1.x,w1.y,w1.z,w1.w};
        #pragma unroll
        for (int e=0;e<8;e++){
          float f = bf2f((ushort)vh[e]) + bf2f((ushort)vl[e]);
          acc = fmaf(f, wv[e], acc);
        }
      }
    }
  }
  float v = acc + db4[0];
  float rcn = 1.f/(1.f + __expf(-v));
  recon[id] = rcn;
  float d = rcn - xref[id];
  float s2 = wred64(d*d);
  __shared__ float red[4];
  if ((threadIdx.x & 63)==0) red[threadIdx.x>>6] = s2;
  __syncthreads();
  if (threadIdx.x==0) atomicAdd(loss + 0, red[0]+red[1]+red[2]+red[3]);
}

// ---------------------------------------------------------------------------
__global__ __launch_bounds__(256) void k_final(
    const float* __restrict__ avgs, const unsigned int* __restrict__ cnt,
    const float* __restrict__ cluster, const float* __restrict__ loss,
    float* __restrict__ dout)
{
  __shared__ float red[3][4];
  int tid = threadIdx.x;
  float e1=0.f, e2=0.f, ac=0.f;
  for (int j=tid; j<8192; j+=256){
    float a = avgs[j] * (1.f/8192.f);
    e1 += a * __logf(a + 1e-10f);
    float h = (float)cnt[j] * (1.f/8192.f);
    e2 += h * __logf(h + 1e-10f);
    ac += (cluster[j] > 1.f) ? 1.f : 0.f;
  }
  e1 = wred64(e1); e2 = wred64(e2); ac = wred64(ac);
  int wv = tid >> 6;
  if ((tid & 63)==0){ red[0][wv]=e1; red[1][wv]=e2; red[2][wv]=ac; }
  __syncthreads();
  if (tid==0){
    float s1 = red[0][0]+red[0][1]+red[0][2]+red[0][3];
    float s2 = red[1][0]+red[1][1]+red[1][2]+red[1][3];
    float s3 = red[2][0]+red[2][1]+red[2][2]+red[2][3];
    float ue = -s1;
    dout[O_RLOSS]  = loss[0] * (1.f/2097152.f);
    float cc = loss[1] * (1.f/524288.f);
    dout[O_COMMIT] = cc;
    dout[O_CB]     = cc;
    dout[O_DIV]    = -ue / 9.010913347279288f;
    dout[O_UE]     = ue;
    dout[O_PERP]   = __expf(-s2);
    dout[O_ACT]    = s3;
  }
}

// ---------------------------------------------------------------------------
extern "C" void kernel_launch(void* const* d_in, const int* in_sizes, int n_in,
                              void* d_out, int out_size, void* d_ws, size_t ws_size,
                              hipStream_t stream)
{
  (void)in_sizes; (void)n_in; (void)out_size; (void)ws_size;
  const float* x     = (const float*)d_in[0];
  const float* ew1   = (const float*)d_in[1];
  const float* eb1   = (const float*)d_in[2];
  const float* bn1s  = (const float*)d_in[3];
  const float* bn1b  = (const float*)d_in[4];
  const float* ew2   = (const float*)d_in[5];
  const float* eb2   = (const float*)d_in[6];
  const float* bn2s  = (const float*)d_in[7];
  const float* bn2b  = (const float*)d_in[8];
  const float* ew3   = (const float*)d_in[9];
  const float* eb3   = (const float*)d_in[10];
  const float* bn3s  = (const float*)d_in[11];
  const float* bn3b  = (const float*)d_in[12];
  const float* ew4   = (const float*)d_in[13];
  const float* eb4   = (const float*)d_in[14];
  const float* embed = (const float*)d_in[15];
  const float* clsz  = (const float*)d_in[16];
  const float* dw1   = (const float*)d_in[17];
  const float* db1   = (const float*)d_in[18];
  const float* dbn1s = (const float*)d_in[19];
  const float* dbn1b = (const float*)d_in[20];
  const float* dw2   = (const float*)d_in[21];
  const float* db2   = (const float*)d_in[22];
  const float* dbn2s = (const float*)d_in[23];
  const float* dbn2b = (const float*)d_in[24];
  const float* dw3   = (const float*)d_in[25];
  const float* db3   = (const float*)d_in[26];
  const float* dbn3s = (const float*)d_in[27];
  const float* dbn3b = (const float*)d_in[28];
  const float* dw4   = (const float*)d_in[29];
  const float* db4   = (const float*)d_in[30];

  float* out = (float*)d_out;
  uint8_t* wsb = (uint8_t*)d_ws;

  float*  A1   = (float*)(wsb + WS_R1);
  float*  dist = (float*)(wsb + WS_R1);
  ushort* D3h  = (ushort*)(wsb + WS_R1);
  ushort* D3l  = (ushort*)(wsb + WS_R1 + 67108864ull);
  float*  A2   = (float*)(wsb + WS_R2);
  ushort* D2h  = (ushort*)(wsb + WS_R2);
  ushort* D2l  = (ushort*)(wsb + WS_R2 + 17301504ull);
  float*  A3   = (float*)(wsb + WS_R3);
  ushort* D1h  = (ushort*)(wsb + WS_R3);
  ushort* D1l  = (ushort*)(wsb + WS_R3 + 8912896ull);
  float*  flat = (float*)(wsb + WS_FLAT);
  ushort* zqPh = (ushort*)(wsb + WS_ZQP);
  ushort* zqPl = (ushort*)(wsb + WS_ZQP + 1179648ull);

  ushort* wE2h = (ushort*)(wsb + WT_E2);
  ushort* wE2m = wE2h + 65536;  ushort* wE2l = wE2m + 65536;
  ushort* wE3h = (ushort*)(wsb + WT_E3);
  ushort* wE3m = wE3h + 131072; ushort* wE3l = wE3m + 131072;
  ushort* wE4h = (ushort*)(wsb + WT_E4);
  ushort* wE4m = wE4h + 131072; ushort* wE4l = wE4m + 131072;
  ushort* wD1h = (ushort*)(wsb + WT_D1);
  ushort* wD1l = wD1h + 131072;
  ushort* wD2h = (ushort*)(wsb + WT_D2);
  ushort* wD2l = wD2h + 131072;
  ushort* wD3h = (ushort*)(wsb + WT_D3);
  ushort* wD3l = wD3h + 65536;
  float*  w4   = (float*)(wsb + WS_W4);

  unsigned long long* rmp = (unsigned long long*)(wsb + ST_RMP);
  unsigned int* cnt = (unsigned int*)(wsb + ST_CNT);
  float* avgs   = (float*)(wsb + ST_AVGS);
  float* rowzi  = (float*)(wsb + ST_ROWZI);
  float* codesq = (float*)(wsb + ST_CODESQ);
  float* loss   = (float*)(wsb + ST_LOSS);

  dim3 B(256);

  k_init<<<32, B, 0, stream>>>(avgs, cnt, rmp, loss);

  // weight prep
  k_wsplit<<<256, B, 0, stream>>>(ew2, wE2h, wE2m, wE2l, 64, 64, 0, 1);
  k_wsplit<<<512, B, 0, stream>>>(ew3, wE3h, wE3m, wE3l, 128, 64, 0, 1);
  k_wsplit<<<512, B, 0, stream>>>(ew4, wE4h, wE4m, wE4l, 64, 128, 0, 1);
  k_wsplit<<<512, B, 0, stream>>>(dw1, wD1h, nullptr, wD1l, 128, 64, 1, 0);
  k_wsplit<<<512, B, 0, stream>>>(dw2, wD2h, nullptr, wD2l, 64, 128, 1, 0);
  k_wsplit<<<256, B, 0, stream>>>(dw3, wD3h, nullptr, wD3l, 64, 64, 1, 0);
  k_w4prep<<<4, B, 0, stream>>>(dw4, w4);

  // zero x-pad columns of padded fp32 encoder tensors + zqP
  k_zpad<<<1024, B, 0, stream>>>((unsigned*)A2, nullptr, 32*64, 66, 64);
  k_zpad<<<1024, B, 0, stream>>>((unsigned*)A3, nullptr, 32*32, 34, 128);
  k_zpad<<<128,  B, 0, stream>>>((unsigned*)zqPh, (unsigned*)zqPl, 32*16, 18, 32);

  // encoder
  enc_conv1<<<2048, B, 0, stream>>>(x, ew1, eb1, bn1s, bn1b, A1);
  enc_conv<64,64,64,64,128,128,false,false><<<2048, B, 0, stream>>>(
      A1, wE2h, wE2m, wE2l, eb2, bn2s, bn2b, A2, 1);
  enc_conv<64,128,32,32,64,64,true,false><<<1024, B, 0, stream>>>(
      A2, wE3h, wE3m, wE3l, eb3, bn3s, bn3b, A3, 2);
  enc_conv<128,64,16,16,32,32,true,true><<<128, B, 0, stream>>>(
      A3, wE4h, wE4m, wE4l, eb4, eb4, eb4, flat, 1);

  // D-pads (A3 now dead after next kernels... zero after conv4 consumed A3)
  // (placed after conv4 below)

  k_codesq<<<2048, B, 0, stream>>>(embed, codesq);

  // zero pad cols of decoder tensors (regions free now: A2/A3 consumed)
  k_zpad<<<512, B, 0, stream>>>((unsigned*)D1h, (unsigned*)D1l, 32*32, 34, 64);
  k_zpad<<<512, B, 0, stream>>>((unsigned*)D2h, (unsigned*)D2l, 32*64, 66, 32);

  // VQ in 2 row chunks (dist reuses dead A1 region)
  for (int chunk = 0; chunk < 2; chunk++){
    int rb = chunk * 4096;
    vq_gemm_mfma<<<2048, B, 0, stream>>>(flat, embed, codesq, dist, rmp, rb);
    vq_rowz<<<512, B, 0, stream>>>(dist, rmp, rowzi, rb);
    vq_colsum<<<256, B, 0, stream>>>(dist, rmp, rowzi, avgs, rb);
  }
  vq_post<<<2048, B, 0, stream>>>(flat, embed, rmp, out + O_CODES, out + O_ZQ,
                                  zqPh, zqPl, loss, cnt);

  // decoder
  dec_convT<64,128,16,16,true><<<1024, B, 0, stream>>>(
      zqPh, zqPl, wD1h, wD1l, db1, dbn1s, dbn1b, D1h, D1l, 2);
  dec_convT<128,64,32,32,true><<<2048, B, 0, stream>>>(
      D1h, D1l, wD2h, wD2l, db2, dbn2s, dbn2b, D2h, D2l, 1);
  dec_convT<64,64,64,64,false><<<8192, B, 0, stream>>>(
      D2h, D2l, wD3h, wD3l, db3, dbn3s, dbn3b, D3h, D3l, 1);
  dec_convT4<<<8192, B, 0, stream>>>(D3h, D3l, w4, db4, x, out + O_RECON, loss);

  k_final<<<1, B, 0, stream>>>(avgs, cnt, clsz, loss, out);
}

// Round 3
// 1367.383 us; speedup vs baseline: 1.4326x; 1.1788x over previous
//
#include <hip/hip_runtime.h>
#include <cstdint>
#include <cstddef>

// ---------------------------------------------------------------------------
// VQ-VAE forward, MFMA split-bf16 implementation (gfx950).
//  encoder convs: fp32 NHWC activations, 3-way-split weights+activations at
//    LDS stage time, 6 MFMA terms per K16 tile  (~fp32 accuracy for argmin)
//  decoder convT1/2: bf16 hi/lo NHWC activations, 2-way split, 3 MFMA terms
//  convT3 writes f32 NHWC; convT4 is LDS-tiled fp32 (fused sigmoid+loss)
//  VQ: dist GEMM via MFMA (row-const dropped), dist chunked into dead A1 region
// ---------------------------------------------------------------------------

#define DEVI __device__ __forceinline__

typedef short  short8 __attribute__((ext_vector_type(8)));
typedef __bf16 bf16x8 __attribute__((ext_vector_type(8)));
typedef float  f32x16 __attribute__((ext_vector_type(16)));

DEVI f32x16 MFMA(bf16x8 a, bf16x8 b, f32x16 c){
  return __builtin_amdgcn_mfma_f32_32x32x16_bf16(a, b, c, 0, 0, 0);
}

DEVI ushort f2bf(float f){
  unsigned u = __float_as_uint(f);
  unsigned r = (u + 0x7FFFu + ((u >> 16) & 1u)) >> 16;
  return (ushort)r;
}
DEVI float bf2f(ushort h){ return __uint_as_float(((unsigned)h) << 16); }

DEVI float wred64(float v){
  #pragma unroll
  for (int off=32; off>0; off>>=1) v += __shfl_down(v, off, 64);
  return v;
}
DEVI float wred32(float v){
  #pragma unroll
  for (int off=16; off>0; off>>=1) v += __shfl_down(v, off, 32);
  return v;
}

// ---- output layout (float32 elements) ----
#define O_RECON     0
#define O_RLOSS     2097152
#define O_CODES     2097153
#define O_ZQ        2105345
#define O_COMMIT    2629633
#define O_CB        2629634
#define O_DIV       2629635
#define O_UE        2629636
#define O_PERP      2629637
#define O_ACT       2629638

// ---- workspace layout (bytes) ----
// R1: A1 fp32 [32][128][128][64] | dist chunk [4096][8192] f32 | D3 f32 NHWC
#define WS_R1       0ull                       // 134,217,728
#define WS_R2       134217728ull               // A2 fp32 [32][64][66][64] | D2 h+l   34,603,008
#define WS_R3       168820736ull               // A3 fp32 [32][32][34][128] | D1 h+l  17,825,792
#define WS_FLAT     186646528ull               // fp32 [8192][64]  2,097,152
#define WS_ZQP      188743680ull               // zqP h (1,179,648) + l
#define WS_WT       191102976ull
#define WT_E2       (WS_WT)                    // 3 x 131,072
#define WT_E3       (WT_E2 + 393216ull)        // 3 x 262,144
#define WT_E4       (WT_E3 + 786432ull)        // 3 x 262,144
#define WT_D1       (WT_E4 + 786432ull)        // 2 x 262,144
#define WT_D2       (WT_D1 + 524288ull)        // 2 x 262,144
#define WT_D3       (WT_D2 + 524288ull)        // 2 x 131,072
#define WS_W4       (WT_D3 + 262144ull)        // 4,096 fp32 [16][64]
#define WS_STATS    (WS_W4 + 4096ull)          // = 194,387,968
#define ST_RMP      (WS_STATS)                 // 65,536
#define ST_CNT      (ST_RMP + 65536ull)        // 32,768
#define ST_AVGS     (ST_CNT + 32768ull)
#define ST_ROWZI    (ST_AVGS + 32768ull)
#define ST_CODESQ   (ST_ROWZI + 32768ull)
#define ST_LOSS     (ST_CODESQ + 32768ull)     // 256 B

// ---------------------------------------------------------------------------
__global__ __launch_bounds__(256) void k_init(float* __restrict__ avgs,
                                              unsigned int* __restrict__ cnt,
                                              unsigned long long* __restrict__ rmp,
                                              float* __restrict__ loss)
{
  int i = blockIdx.x*256 + threadIdx.x;
  if (i < 8192){ avgs[i]=0.f; cnt[i]=0u; rmp[i]=0xFFFFFFFFFFFFFFFFull; }
  if (i < 8) loss[i]=0.f;
}

// weight transform+split: src OIHW fp32 -> dst [16][OC][CIN] bf16 (3- or 2-way)
__global__ __launch_bounds__(256) void k_wsplit(
    const float* __restrict__ src, ushort* __restrict__ dh,
    ushort* __restrict__ dm, ushort* __restrict__ dl,
    int OC, int CIN, int isT, int three)
{
  int i = blockIdx.x*256 + threadIdx.x;
  if (i >= 16*OC*CIN) return;
  int cin = i % CIN; int t = i / CIN; int oc = t % OC; int tap = t / OC;
  int st;
  if (isT){
    int pq = tap>>2, ab = tap&3;
    int p = pq>>1, q = pq&1, a = ab>>1, b = ab&1;
    st = (p + 2*a)*4 + (q + 2*b);
  } else st = tap;
  float v = src[((size_t)oc*CIN + cin)*16 + st];
  ushort h = f2bf(v); float r = v - bf2f(h);
  if (three){
    ushort m = f2bf(r); float r2 = r - bf2f(m);
    dm[i] = m; dl[i] = f2bf(r2);
  } else {
    dl[i] = f2bf(r);
  }
  dh[i] = h;
}

__global__ __launch_bounds__(256) void k_w4prep(const float* __restrict__ dw4,
                                                float* __restrict__ w4)
{
  int i = blockIdx.x*256 + threadIdx.x;
  if (i >= 1024) return;
  int c = i & 63; int t16 = i >> 6;
  int pq = t16 >> 2, ab = t16 & 3;
  int p = pq>>1, q = pq&1, a = ab>>1, b = ab&1;
  w4[i] = dw4[(size_t)c*16 + (p+2*a)*4 + (q+2*b)];
}

// zero the x-pad columns (col 0 and Wp-1). cwords = C*elemBytes/4.
__global__ __launch_bounds__(256) void k_zpad(unsigned* __restrict__ b0,
                                              unsigned* __restrict__ b1,
                                              int rows, int Wp, int cwords)
{
  int i = blockIdx.x*256 + threadIdx.x;
  int total = rows*2*cwords;
  if (i >= total) return;
  int pos = i / cwords, cw = i % cwords;
  int row = pos >> 1, side = pos & 1;
  size_t w = ((size_t)row*Wp + (side ? (Wp-1) : 0))*cwords + cw;
  b0[w] = 0u;
  if (b1) b1[w] = 0u;
}

// ---------------------------------------------------------------------------
// conv1: 1->64ch, k4 s2 p1, direct fp32, writes NHWC fp32 [32][128][128][64]
// ---------------------------------------------------------------------------
__global__ __launch_bounds__(256) void enc_conv1(
    const float* __restrict__ x, const float* __restrict__ w,
    const float* __restrict__ cb_, const float* __restrict__ bns,
    const float* __restrict__ bnb, float* __restrict__ out)
{
  __shared__ __align__(16) float sIn[34][36];
  __shared__ __align__(16) float sW[64][16];
  int b = blockIdx.x;
  int t = b & 63, n = b >> 6;
  int ty = t >> 3, tx = t & 7;
  int oy0 = ty*16, ox0 = tx*16;
  int iy0 = 2*oy0 - 1, ix0 = 2*ox0 - 1;
  int tid = threadIdx.x;
  int spg = tid & 31, og = tid >> 5;
  int sy = spg >> 1, x0 = (spg & 1)*8;

  if (tid < 64){
    const float* wp = w + tid*16;
    *(float4*)&sW[tid][0]  = *(const float4*)(wp);
    *(float4*)&sW[tid][4]  = *(const float4*)(wp+4);
    *(float4*)&sW[tid][8]  = *(const float4*)(wp+8);
    *(float4*)&sW[tid][12] = *(const float4*)(wp+12);
  }
  for (int e = tid; e < 34*34; e += 256){
    int rr = e/34, cc = e%34;
    int iy = iy0+rr, ix = ix0+cc;
    float v = 0.f;
    if ((unsigned)iy < 256u && (unsigned)ix < 256u)
      v = x[(size_t)n*65536 + iy*256 + ix];
    sIn[rr][cc] = v;
  }
  __syncthreads();

  float acc[8][8];
  #pragma unroll
  for (int j=0;j<8;j++)
    #pragma unroll
    for (int xi=0;xi<8;xi++) acc[j][xi]=0.f;

  #pragma unroll
  for (int ky=0; ky<4; ky++){
    int riy = 2*sy + ky;
    float seg[20];
    #pragma unroll
    for (int i=0;i<5;i++){
      float4 v = *(const float4*)&sIn[riy][2*x0 + 4*i];
      seg[4*i+0]=v.x; seg[4*i+1]=v.y; seg[4*i+2]=v.z; seg[4*i+3]=v.w;
    }
    #pragma unroll
    for (int j=0;j<8;j++){
      float4 w4v = *(const float4*)&sW[og*8+j][ky*4];
      #pragma unroll
      for (int xi=0; xi<8; xi++){
        acc[j][xi] = fmaf(seg[2*xi+0], w4v.x,
                     fmaf(seg[2*xi+1], w4v.y,
                     fmaf(seg[2*xi+2], w4v.z,
                     fmaf(seg[2*xi+3], w4v.w, acc[j][xi]))));
      }
    }
  }

  float sc[8], sh[8];
  #pragma unroll
  for (int j=0;j<8;j++){
    int oc = og*8+j;
    sc[j] = bns[oc];
    sh[j] = fmaf(cb_[oc], sc[j], bnb[oc]);
  }
  int oy = oy0 + sy;
  #pragma unroll
  for (int xi=0; xi<8; xi++){
    int oxg = ox0 + x0 + xi;
    float* op = out + (((size_t)n*128 + oy)*128 + oxg)*64 + og*8;
    float4 q0, q1;
    q0.x = fmaxf(fmaf(acc[0][xi], sc[0], sh[0]), 0.f);
    q0.y = fmaxf(fmaf(acc[1][xi], sc[1], sh[1]), 0.f);
    q0.z = fmaxf(fmaf(acc[2][xi], sc[2], sh[2]), 0.f);
    q0.w = fmaxf(fmaf(acc[3][xi], sc[3], sh[3]), 0.f);
    q1.x = fmaxf(fmaf(acc[4][xi], sc[4], sh[4]), 0.f);
    q1.y = fmaxf(fmaf(acc[5][xi], sc[5], sh[5]), 0.f);
    q1.z = fmaxf(fmaf(acc[6][xi], sc[6], sh[6]), 0.f);
    q1.w = fmaxf(fmaf(acc[7][xi], sc[7], sh[7]), 0.f);
    *(float4*)op     = q0;
    *(float4*)(op+4) = q1;
  }
}

// ---------------------------------------------------------------------------
// Encoder conv k4 s2 p1 as tap-GEMM, 3-way-split MFMA (6 terms).
// in: fp32 NHWC [32][INH][INWP][CIN]; out: fp32 NHWC padded, or flat.
// block = 256 thr (4 waves 2x2), tile M=64 x N=64, taps 16 x K=CIN.
// ---------------------------------------------------------------------------
template<int CIN, int OC, int OUTW, int OUTH, int INW, int INH, bool XPAD, bool TOFLAT>
__global__ __launch_bounds__(256) void enc_conv(
    const float* __restrict__ in,
    const ushort* __restrict__ wtH, const ushort* __restrict__ wtM,
    const ushort* __restrict__ wtL,
    const float* __restrict__ cb_, const float* __restrict__ bns,
    const float* __restrict__ bnb,
    float* __restrict__ out, int nOcg)
{
  constexpr int INWP  = XPAD ? (INW+2) : INW;
  constexpr int WP    = INW + 2;
  constexpr int NROWS = 64 / OUTW;
  constexpr int AELEM = NROWS * WP * CIN;
  constexpr int BCIN  = (CIN > 64) ? 64 : CIN;
  constexpr int BELEM = 64 * BCIN;
  constexpr int SCRSZ = (3*BELEM*2 > 64*68*4) ? 3*BELEM*2 : 64*68*4;

  __shared__ __align__(16) ushort sAh[AELEM], sAm[AELEM], sAl[AELEM];
  __shared__ __align__(16) char sScr[SCRSZ];
  ushort* sBh = (ushort*)sScr;
  ushort* sBm = sBh + BELEM;
  ushort* sBl = sBm + BELEM;
  float*  sC  = (float*)sScr;

  int b = blockIdx.x;
  int ocg = b % nOcg; b /= nOcg;
  int yb  = b % (OUTH/NROWS); b /= (OUTH/NROWS);
  int n = b;
  int oy0 = yb * NROWS, oc0 = ocg * 64;

  int tid = threadIdx.x;
  int l = tid & 63, wave = tid >> 6;
  int wm = wave >> 1, wn = wave & 1;
  int r = l & 31, kp = l >> 5;
  int idx = wm*32 + r;
  int oy_off = idx / OUTW, ox = idx % OUTW;

  f32x16 acc;
  #pragma unroll
  for (int i=0;i<16;i++) acc[i] = 0.f;

  const size_t nbase = (size_t)n * INH * INWP * CIN;

  for (int ky = 0; ky < 4; ky++){
    __syncthreads();
    // ---- stage + 3-split A rows for this ky ----
    for (int c = tid; c < AELEM/8; c += 256){
      int j  = c / (WP*CIN/8);
      int rm = c % (WP*CIN/8);
      int lx = rm / (CIN/8);
      int c8 = (rm % (CIN/8)) * 8;
      int iy = 2*(oy0 + j) - 1 + ky;
      bool ok = (unsigned)iy < (unsigned)INH;
      int gx = XPAD ? lx : (lx - 1);
      if (!XPAD) ok = ok && ((unsigned)gx < (unsigned)INW);
      float4 v0 = {0,0,0,0}, v1 = {0,0,0,0};
      if (ok){
        const float* s = in + nbase + ((size_t)iy*INWP + gx)*CIN + c8;
        v0 = *(const float4*)s; v1 = *(const float4*)(s+4);
      }
      float vv[8] = {v0.x,v0.y,v0.z,v0.w,v1.x,v1.y,v1.z,v1.w};
      short8 hh, mm, ll;
      #pragma unroll
      for (int e=0;e<8;e++){
        ushort h = f2bf(vv[e]); float r1 = vv[e] - bf2f(h);
        ushort m = f2bf(r1);    float r2 = r1 - bf2f(m);
        hh[e] = (short)h; mm[e] = (short)m; ll[e] = (short)f2bf(r2);
      }
      unsigned off = (unsigned)(((j*WP + lx)*CIN + c8)*2) ^ ((((unsigned)lx>>1)&7u)<<4);
      *(short8*)((char*)sAh + off) = hh;
      *(short8*)((char*)sAm + off) = mm;
      *(short8*)((char*)sAl + off) = ll;
    }
    for (int kx = 0; kx < 4; kx++){
      int tap = ky*4 + kx;
      for (int ch = 0; ch < CIN; ch += BCIN){
        __syncthreads();
        // ---- stage B (pre-split weights) ----
        for (int c = tid; c < BELEM/8; c += 256){
          int oc = c / (BCIN/8);
          int c8 = (c % (BCIN/8)) * 8;
          size_t s = ((size_t)tap*OC + oc0 + oc)*CIN + ch + c8;
          unsigned off = (unsigned)((oc*BCIN + c8)*2) ^ (((unsigned)oc&7u)<<4);
          *(short8*)((char*)sBh + off) = *(const short8*)(wtH + s);
          *(short8*)((char*)sBm + off) = *(const short8*)(wtM + s);
          *(short8*)((char*)sBl + off) = *(const short8*)(wtL + s);
        }
        __syncthreads();
        int lx = 2*ox + kx;
        unsigned asw  = ((((unsigned)lx>>1)&7u)<<4);
        unsigned alin = (unsigned)(((oy_off*WP + lx)*CIN)*2);
        int ocl = wn*32 + r;
        unsigned bsw  = (((unsigned)ocl&7u)<<4);
        unsigned blin = (unsigned)((ocl*BCIN)*2);
        #pragma unroll
        for (int ct = 0; ct < BCIN/16; ct++){
          unsigned kbA = (unsigned)((ch + ct*16 + kp*8)*2);
          unsigned kbB = (unsigned)((ct*16 + kp*8)*2);
          unsigned ao = (alin + kbA) ^ asw;
          unsigned bo = (blin + kbB) ^ bsw;
          bf16x8 ah = *(const bf16x8*)((char*)sAh + ao);
          bf16x8 am = *(const bf16x8*)((char*)sAm + ao);
          bf16x8 al = *(const bf16x8*)((char*)sAl + ao);
          bf16x8 bh = *(const bf16x8*)((char*)sBh + bo);
          bf16x8 bm = *(const bf16x8*)((char*)sBm + bo);
          bf16x8 bl = *(const bf16x8*)((char*)sBl + bo);
          acc = MFMA(ah, bh, acc);
          acc = MFMA(ah, bm, acc);
          acc = MFMA(am, bh, acc);
          acc = MFMA(ah, bl, acc);
          acc = MFMA(am, bm, acc);
          acc = MFMA(al, bh, acc);
        }
      }
    }
  }
  // ---- epilogue via LDS transpose ----
  __syncthreads();
  #pragma unroll
  for (int q = 0; q < 16; q++){
    int rowt = (q&3) + 8*(q>>2) + 4*kp;
    sC[(wm*32 + rowt)*68 + wn*32 + r] = acc[q];
  }
  __syncthreads();
  {
    int e = tid;
    int m = e >> 2, qq = e & 3;
    int oc = oc0 + qq*16;
    int oyg = oy0 + m / OUTW;
    int oxg = m % OUTW;
    if (TOFLAT){
      size_t row = (size_t)n*256 + oyg*16 + oxg;
      float* op = out + row*64 + qq*16;
      #pragma unroll
      for (int i=0;i<16;i+=4){
        float4 o4;
        o4.x = sC[m*68 + qq*16 + i+0] + cb_[oc+i+0];
        o4.y = sC[m*68 + qq*16 + i+1] + cb_[oc+i+1];
        o4.z = sC[m*68 + qq*16 + i+2] + cb_[oc+i+2];
        o4.w = sC[m*68 + qq*16 + i+3] + cb_[oc+i+3];
        *(float4*)(op + i) = o4;
      }
    } else {
      float* op = out + (((size_t)n*OUTH + oyg)*(OUTW+2) + oxg + 1)*OC + oc;
      #pragma unroll
      for (int i=0;i<16;i+=4){
        float4 o4; float tmp[4];
        #pragma unroll
        for (int u=0; u<4; u++){
          float s1 = bns[oc+i+u];
          float s2 = fmaf(cb_[oc+i+u], s1, bnb[oc+i+u]);
          tmp[u] = fmaxf(fmaf(sC[m*68 + qq*16 + i+u], s1, s2), 0.f);
        }
        o4.x=tmp[0]; o4.y=tmp[1]; o4.z=tmp[2]; o4.w=tmp[3];
        *(float4*)(op + i) = o4;
      }
    }
  }
}

// ---------------------------------------------------------------------------
__global__ __launch_bounds__(256) void k_codesq(const float* __restrict__ embed,
                                                float* __restrict__ codesq)
{
  int j = blockIdx.x*4 + (threadIdx.x>>6);
  int c = threadIdx.x & 63;
  float e = embed[(size_t)j*64 + c];
  float s = wred64(e*e);
  if (c==0) codesq[j] = s;
}

DEVI float rmp_minval(unsigned long long v){
  unsigned skey = (unsigned)(v >> 32);
  unsigned u = (skey & 0x80000000u) ? (skey ^ 0x80000000u) : ~skey;
  return __uint_as_float(u);
}

// ---------------------------------------------------------------------------
// VQ dist GEMM: 128x128 tile, K=64, 3-way-split MFMA (6 terms).
// dist'[i][j] = |e_j|^2 - 2 f_i.e_j   (row constant dropped; argmin/softmax inv.)
// ---------------------------------------------------------------------------
__global__ __launch_bounds__(256) void vq_gemm_mfma(
    const float* __restrict__ flat, const float* __restrict__ embed,
    const float* __restrict__ codesq, float* __restrict__ dist,
    unsigned long long* __restrict__ rmp, int row_base)
{
  __shared__ __align__(16) ushort sAh[128*64], sAm[128*64], sAl[128*64];
  __shared__ __align__(16) ushort sBh[128*64], sBm[128*64], sBl[128*64];
  int cb = blockIdx.x & 63, rb = blockIdx.x >> 6;
  int rloc0 = rb*128, row0 = row_base + rloc0, c0 = cb*128;
  int tid = threadIdx.x, l = tid&63, wave = tid>>6;
  int wm = wave>>1, wn = wave&1, r = l&31, kp = l>>5;

  for (int c = tid; c < 2048; c += 256){
    int isB = c >> 10, cc = c & 1023;
    int rr = cc >> 3, c8 = (cc & 7)*8;
    const float* s = (isB ? (embed + (size_t)(c0+rr)*64)
                          : (flat  + (size_t)(row0+rr)*64)) + c8;
    float4 v0 = *(const float4*)s, v1 = *(const float4*)(s+4);
    float vv[8] = {v0.x,v0.y,v0.z,v0.w,v1.x,v1.y,v1.z,v1.w};
    short8 hh, mm, ll;
    #pragma unroll
    for (int e=0;e<8;e++){
      ushort h = f2bf(vv[e]); float r1 = vv[e] - bf2f(h);
      ushort m = f2bf(r1);    float r2 = r1 - bf2f(m);
      hh[e]=(short)h; mm[e]=(short)m; ll[e]=(short)f2bf(r2);
    }
    unsigned off = (unsigned)((rr*64 + c8)*2) ^ (((unsigned)rr&7u)<<4);
    if (isB){
      *(short8*)((char*)sBh + off) = hh;
      *(short8*)((char*)sBm + off) = mm;
      *(short8*)((char*)sBl + off) = ll;
    } else {
      *(short8*)((char*)sAh + off) = hh;
      *(short8*)((char*)sAm + off) = mm;
      *(short8*)((char*)sAl + off) = ll;
    }
  }
  __syncthreads();

  f32x16 acc[2][2];
  #pragma unroll
  for (int mt=0;mt<2;mt++)
    #pragma unroll
    for (int nt=0;nt<2;nt++)
      #pragma unroll
      for (int i=0;i<16;i++) acc[mt][nt][i]=0.f;

  #pragma unroll
  for (int ks=0; ks<4; ks++){
    unsigned kb = (unsigned)((ks*16 + kp*8)*2);
    bf16x8 Ah[2],Am[2],Al[2],Bh[2],Bm[2],Bl[2];
    #pragma unroll
    for (int mt=0;mt<2;mt++){
      int rowi = wm*64 + mt*32 + r;
      unsigned o = ((unsigned)(rowi*128) + kb) ^ (((unsigned)rowi&7u)<<4);
      Ah[mt] = *(const bf16x8*)((char*)sAh + o);
      Am[mt] = *(const bf16x8*)((char*)sAm + o);
      Al[mt] = *(const bf16x8*)((char*)sAl + o);
    }
    #pragma unroll
    for (int nt=0;nt<2;nt++){
      int coli = wn*64 + nt*32 + r;
      unsigned o = ((unsigned)(coli*128) + kb) ^ (((unsigned)coli&7u)<<4);
      Bh[nt] = *(const bf16x8*)((char*)sBh + o);
      Bm[nt] = *(const bf16x8*)((char*)sBm + o);
      Bl[nt] = *(const bf16x8*)((char*)sBl + o);
    }
    #pragma unroll
    for (int mt=0;mt<2;mt++)
      #pragma unroll
      for (int nt=0;nt<2;nt++){
        acc[mt][nt] = MFMA(Ah[mt], Bh[nt], acc[mt][nt]);
        acc[mt][nt] = MFMA(Ah[mt], Bm[nt], acc[mt][nt]);
        acc[mt][nt] = MFMA(Am[mt], Bh[nt], acc[mt][nt]);
        acc[mt][nt] = MFMA(Ah[mt], Bl[nt], acc[mt][nt]);
        acc[mt][nt] = MFMA(Am[mt], Bm[nt], acc[mt][nt]);
        acc[mt][nt] = MFMA(Al[mt], Bh[nt], acc[mt][nt]);
      }
  }

  float cq[2];
  cq[0] = codesq[c0 + wn*64 + r];
  cq[1] = codesq[c0 + wn*64 + 32 + r];
  #pragma unroll
  for (int mt=0; mt<2; mt++){
    #pragma unroll
    for (int q=0; q<16; q++){
      int rowt = (q&3) + 8*(q>>2) + 4*kp;
      int grow = rloc0 + wm*64 + mt*32 + rowt;
      unsigned long long kmin = 0xFFFFFFFFFFFFFFFFull;
      #pragma unroll
      for (int nt=0; nt<2; nt++){
        int col = c0 + wn*64 + nt*32 + r;
        float d = cq[nt] - 2.f*acc[mt][nt][q];
        dist[(size_t)grow*8192 + col] = d;
        unsigned u = __float_as_uint(d);
        unsigned sgn = (unsigned)((int)u >> 31);
        unsigned skey = u ^ (sgn | 0x80000000u);
        unsigned long long key = (((unsigned long long)skey)<<32) | (unsigned)col;
        if (key < kmin) kmin = key;
      }
      #pragma unroll
      for (int off2=16; off2>0; off2>>=1){
        unsigned long long o2 = __shfl_xor(kmin, off2, 64);
        if (o2 < kmin) kmin = o2;
      }
      if (r == 0) atomicMin(&rmp[row_base + grow], kmin);
    }
  }
}

// 1/Z per row
__global__ __launch_bounds__(256) void vq_rowz(
    const float* __restrict__ dist, const unsigned long long* __restrict__ rmp,
    float* __restrict__ rowzi, int row_base)
{
  int rl = threadIdx.x >> 5, lane = threadIdx.x & 31;
  int rloc = blockIdx.x*8 + rl;
  int row = row_base + rloc;
  float m = rmp_minval(rmp[row]);
  const float* dp = dist + (size_t)rloc*8192;
  float s = 0.f;
  for (int c = lane*4; c < 8192; c += 128){
    float4 v = *(const float4*)(dp + c);
    s += __expf(m - v.x) + __expf(m - v.y) + __expf(m - v.z) + __expf(m - v.w);
  }
  s = wred32(s);
  if (lane==0) rowzi[row] = 1.f / s;
}

__global__ __launch_bounds__(256) void vq_colsum(
    const float* __restrict__ dist, const unsigned long long* __restrict__ rmp,
    const float* __restrict__ rowzi, float* __restrict__ avgs, int row_base)
{
  int j = (blockIdx.x & 31)*256 + threadIdx.x;
  int rg = blockIdx.x >> 5;
  float s = 0.f;
  for (int i = rg*512; i < rg*512 + 512; i++){
    int row = row_base + i;
    float m = rmp_minval(rmp[row]);
    float zi = rowzi[row];
    s = fmaf(__expf(m - dist[(size_t)i*8192 + j]), zi, s);
  }
  atomicAdd(avgs + j, s);
}

// codes, zq (fp32 NCHW out), zqP (bf16 hi/lo NHWC padded), commit SSE, hist
__global__ __launch_bounds__(256) void vq_post(
    const float* __restrict__ flat, const float* __restrict__ embed,
    const unsigned long long* __restrict__ rmp,
    float* __restrict__ out_codes, float* __restrict__ out_zq,
    ushort* __restrict__ zqPh, ushort* __restrict__ zqPl,
    float* __restrict__ loss, unsigned int* __restrict__ cnt)
{
  int r = blockIdx.x*4 + (threadIdx.x>>6);
  int c = threadIdx.x & 63;
  unsigned j = (unsigned)(rmp[r] & 0xFFFFFFFFull);
  float e = embed[(size_t)j*64 + c];
  float f = flat[(size_t)r*64 + c];
  int n = r>>8, rem = r&255, gy = rem>>4, gx = rem&15;
  out_zq[(((size_t)n*64 + c)*16 + gy)*16 + gx] = e;
  ushort h = f2bf(e);
  size_t pz = (((size_t)n*16 + gy)*18 + gx + 1)*64 + c;
  zqPh[pz] = h; zqPl[pz] = f2bf(e - bf2f(h));
  float d = f - e;
  float s2 = wred64(d*d);
  if (c==0){
    out_codes[r] = (float)j;
    atomicAdd(cnt + j, 1u);
    atomicAdd(loss + 1, s2);
  }
}

// ---------------------------------------------------------------------------
// Decoder convT k4 s2 p1 as parity-class tap-GEMM, 2-way-split MFMA (3 terms).
// in: bf16 hi/lo NHWC x-padded [32][SH][SW+2][CIN]; out bf16 hi/lo NHWC,
// or f32 NHWC when OMODE==1.
// grid: n * (SH/TR) * nOcg * 4parities, block 256.
// ---------------------------------------------------------------------------
template<int CIN, int OC, int SW, int SH, bool OUTPAD, int OMODE>
__global__ __launch_bounds__(256) void dec_convT(
    const ushort* __restrict__ inH, const ushort* __restrict__ inL,
    const ushort* __restrict__ wtH, const ushort* __restrict__ wtL,
    const float* __restrict__ db, const float* __restrict__ bns,
    const float* __restrict__ bnb,
    ushort* __restrict__ outH, ushort* __restrict__ outL,
    float* __restrict__ outF, int nOcg)
{
  constexpr int TR    = 64 / SW;
  constexpr int NRA   = TR + 1;
  constexpr int WPin  = SW + 2;
  constexpr int AELEM = NRA * WPin * CIN;
  constexpr int BCIN  = (CIN > 64) ? 64 : CIN;
  constexpr int BELEM = 64 * BCIN;
  constexpr int OUTH  = 2*SH;
  constexpr int OW    = OUTPAD ? (2*SW+2) : (2*SW);
  constexpr int SCRSZ = (2*BELEM*2 > 64*68*4) ? 2*BELEM*2 : 64*68*4;

  __shared__ __align__(16) ushort sAh[AELEM], sAl[AELEM];
  __shared__ __align__(16) char sScr[SCRSZ];
  ushort* sBh = (ushort*)sScr;
  ushort* sBl = sBh + BELEM;
  float*  sC  = (float*)sScr;

  int b = blockIdx.x;
  int par = b & 3; b >>= 2;
  int ocg = b % nOcg; b /= nOcg;
  int tb = b % (SH/TR); b /= (SH/TR);
  int n = b;
  int p = par >> 1, q = par & 1;
  int t0 = tb * TR, oc0 = ocg * 64;

  int tid = threadIdx.x, l = tid&63, wave = tid>>6;
  int wm = wave>>1, wn = wave&1;
  int r = l&31, kp = l>>5;
  int idx = wm*32 + r;
  int t_off = idx / SW, s = idx % SW;

  f32x16 acc;
  #pragma unroll
  for (int i=0;i<16;i++) acc[i]=0.f;

  // ---- stage A rows (once) ----
  for (int c = tid; c < AELEM/8; c += 256){
    int j  = c / (WPin*CIN/8);
    int rm = c % (WPin*CIN/8);
    int lx = rm / (CIN/8);
    int c8 = (rm % (CIN/8)) * 8;
    int giy = t0 + p - 1 + j;
    bool ok = (unsigned)giy < (unsigned)SH;
    short8 vh = {0,0,0,0,0,0,0,0}, vl = {0,0,0,0,0,0,0,0};
    if (ok){
      size_t sidx = (((size_t)n*SH + giy)*WPin + lx)*CIN + c8;
      vh = *(const short8*)(inH + sidx);
      vl = *(const short8*)(inL + sidx);
    }
    unsigned off = (unsigned)(((j*WPin + lx)*CIN + c8)*2) ^ (((unsigned)lx&7u)<<4);
    *(short8*)((char*)sAh + off) = vh;
    *(short8*)((char*)sAl + off) = vl;
  }

  for (int ab = 0; ab < 4; ab++){
    int a = ab>>1, bb = ab&1;
    for (int ch = 0; ch < CIN; ch += BCIN){
      __syncthreads();
      for (int c = tid; c < BELEM/8; c += 256){
        int oc = c / (BCIN/8);
        int c8 = (c % (BCIN/8)) * 8;
        size_t sidx = ((size_t)(par*4 + ab)*OC + oc0 + oc)*CIN + ch + c8;
        unsigned off = (unsigned)((oc*BCIN + c8)*2) ^ (((unsigned)oc&7u)<<4);
        *(short8*)((char*)sBh + off) = *(const short8*)(wtH + sidx);
        *(short8*)((char*)sBl + off) = *(const short8*)(wtL + sidx);
      }
      __syncthreads();
      int lx = s + q + bb;
      int rs = t_off + a;
      unsigned asw  = (((unsigned)lx&7u)<<4);
      unsigned alin = (unsigned)(((rs*WPin + lx)*CIN)*2);
      int ocl = wn*32 + r;
      unsigned bsw  = (((unsigned)ocl&7u)<<4);
      unsigned blin = (unsigned)((ocl*BCIN)*2);
      #pragma unroll
      for (int ct = 0; ct < BCIN/16; ct++){
        unsigned kbA = (unsigned)((ch + ct*16 + kp*8)*2);
        unsigned kbB = (unsigned)((ct*16 + kp*8)*2);
        unsigned ao = (alin + kbA) ^ asw;
        unsigned bo = (blin + kbB) ^ bsw;
        bf16x8 ah = *(const bf16x8*)((char*)sAh + ao);
        bf16x8 al = *(const bf16x8*)((char*)sAl + ao);
        bf16x8 bh = *(const bf16x8*)((char*)sBh + bo);
        bf16x8 bl = *(const bf16x8*)((char*)sBl + bo);
        acc = MFMA(ah, bh, acc);
        acc = MFMA(ah, bl, acc);
        acc = MFMA(al, bh, acc);
      }
    }
  }
  __syncthreads();
  #pragma unroll
  for (int qre = 0; qre < 16; qre++){
    int rowt = (qre&3) + 8*(qre>>2) + 4*kp;
    sC[(wm*32 + rowt)*68 + wn*32 + r] = acc[qre];
  }
  __syncthreads();
  {
    int e = tid;
    int m = e >> 2, qq = e & 3;
    int oc = oc0 + qq*16;
    int y  = 2*(t0 + m/SW) + p;
    int xs = m % SW;
    int xp = OUTPAD ? (2*xs + q + 1) : (2*xs + q);
    size_t base = (((size_t)n*OUTH + y)*OW + xp)*OC + oc;
    if constexpr (OMODE == 1){
      #pragma unroll
      for (int i=0;i<16;i+=4){
        float4 o4; float tmp[4];
        #pragma unroll
        for (int u=0; u<4; u++){
          float s1 = bns[oc+i+u];
          float s2 = fmaf(db[oc+i+u], s1, bnb[oc+i+u]);
          tmp[u] = fmaxf(fmaf(sC[m*68 + qq*16 + i+u], s1, s2), 0.f);
        }
        o4.x=tmp[0]; o4.y=tmp[1]; o4.z=tmp[2]; o4.w=tmp[3];
        *(float4*)(outF + base + i) = o4;
      }
    } else {
      short8 h0, h1, l0, l1;
      #pragma unroll
      for (int i=0;i<16;i++){
        float s1 = bns[oc+i];
        float s2 = fmaf(db[oc+i], s1, bnb[oc+i]);
        float v = fmaxf(fmaf(sC[m*68 + qq*16 + i], s1, s2), 0.f);
        ushort h = f2bf(v);
        ushort lo = f2bf(v - bf2f(h));
        if (i < 8){ h0[i]=(short)h; l0[i]=(short)lo; }
        else      { h1[i-8]=(short)h; l1[i-8]=(short)lo; }
      }
      *(short8*)(outH + base)     = h0;
      *(short8*)(outH + base + 8) = h1;
      *(short8*)(outL + base)     = l0;
      *(short8*)(outL + base + 8) = l1;
    }
  }
}

// ---------------------------------------------------------------------------
// convT4: 64->1ch + sigmoid + recon-loss. LDS-tiled: 16x16 out tile / block,
// input halo 10x10x64 f32 staged (stride 68 to spread banks).
// ---------------------------------------------------------------------------
__global__ __launch_bounds__(256) void dec_convT4(
    const float* __restrict__ d3, const float* __restrict__ w4,
    const float* __restrict__ db4, const float* __restrict__ xref,
    float* __restrict__ recon, float* __restrict__ loss)
{
  __shared__ __align__(16) float sT[10*10*68];
  __shared__ __align__(16) float sWt[16*64];
  __shared__ float red[4];
  int b = blockIdx.x;
  int t = b & 255, n = b >> 8;
  int ty = t >> 4, tx = t & 15;
  int y0 = ty*16, x0 = tx*16;
  int r0 = y0/2 - 1, c0 = x0/2 - 1;
  int tid = threadIdx.x;

  *(float4*)&sWt[tid*4] = *(const float4*)(w4 + tid*4);

  const float* base = d3 + (size_t)n*128*128*64;
  for (int e = tid; e < 1600; e += 256){
    int rr = e/160; int rem = e%160; int cc = rem/16; int c4 = (rem%16)*4;
    int gr = r0+rr, gc = c0+cc;
    float4 v = {0,0,0,0};
    if ((unsigned)gr<128u && (unsigned)gc<128u)
      v = *(const float4*)(base + ((size_t)gr*128+gc)*64 + c4);
    *(float4*)&sT[(rr*10+cc)*68 + c4] = v;
  }
  __syncthreads();

  int sy = tid>>4, sx = tid&15;
  int p = sy&1, q = sx&1;
  int lr0 = (sy>>1)+p, lc0 = (sx>>1)+q;
  int par = p*2+q;
  float4 a4 = {0,0,0,0};
  #pragma unroll
  for (int a=0;a<2;a++){
    #pragma unroll
    for (int bb=0;bb<2;bb++){
      const float* ip = &sT[((lr0+a)*10 + lc0+bb)*68];
      const float* wp = &sWt[(par*4+a*2+bb)*64];
      #pragma unroll
      for (int c=0;c<64;c+=4){
        float4 v  = *(const float4*)(ip+c);
        float4 wv = *(const float4*)(wp+c);
        a4.x = fmaf(v.x, wv.x, a4.x);
        a4.y = fmaf(v.y, wv.y, a4.y);
        a4.z = fmaf(v.z, wv.z, a4.z);
        a4.w = fmaf(v.w, wv.w, a4.w);
      }
    }
  }
  float acc = (a4.x + a4.y) + (a4.z + a4.w);
  float v = acc + db4[0];
  float rcn = 1.f/(1.f + __expf(-v));
  int y = y0+sy, x = x0+sx;
  size_t oi = (size_t)n*65536 + (size_t)y*256 + x;
  recon[oi] = rcn;
  float d = rcn - xref[oi];
  float s2 = wred64(d*d);
  if ((tid & 63)==0) red[tid>>6] = s2;
  __syncthreads();
  if (tid==0) atomicAdd(loss + 0, red[0]+red[1]+red[2]+red[3]);
}

// ---------------------------------------------------------------------------
__global__ __launch_bounds__(256) void k_final(
    const float* __restrict__ avgs, const unsigned int* __restrict__ cnt,
    const float* __restrict__ cluster, const float* __restrict__ loss,
    float* __restrict__ dout)
{
  __shared__ float red[3][4];
  int tid = threadIdx.x;
  float e1=0.f, e2=0.f, ac=0.f;
  for (int j=tid; j<8192; j+=256){
    float a = avgs[j] * (1.f/8192.f);
    e1 += a * __logf(a + 1e-10f);
    float h = (float)cnt[j] * (1.f/8192.f);
    e2 += h * __logf(h + 1e-10f);
    ac += (cluster[j] > 1.f) ? 1.f : 0.f;
  }
  e1 = wred64(e1); e2 = wred64(e2); ac = wred64(ac);
  int wv = tid >> 6;
  if ((tid & 63)==0){ red[0][wv]=e1; red[1][wv]=e2; red[2][wv]=ac; }
  __syncthreads();
  if (tid==0){
    float s1 = red[0][0]+red[0][1]+red[0][2]+red[0][3];
    float s2 = red[1][0]+red[1][1]+red[1][2]+red[1][3];
    float s3 = red[2][0]+red[2][1]+red[2][2]+red[2][3];
    float ue = -s1;
    dout[O_RLOSS]  = loss[0] * (1.f/2097152.f);
    float cc = loss[1] * (1.f/524288.f);
    dout[O_COMMIT] = cc;
    dout[O_CB]     = cc;
    dout[O_DIV]    = -ue / 9.010913347279288f;
    dout[O_UE]     = ue;
    dout[O_PERP]   = __expf(-s2);
    dout[O_ACT]    = s3;
  }
}

// ---------------------------------------------------------------------------
extern "C" void kernel_launch(void* const* d_in, const int* in_sizes, int n_in,
                              void* d_out, int out_size, void* d_ws, size_t ws_size,
                              hipStream_t stream)
{
  (void)in_sizes; (void)n_in; (void)out_size; (void)ws_size;
  const float* x     = (const float*)d_in[0];
  const float* ew1   = (const float*)d_in[1];
  const float* eb1   = (const float*)d_in[2];
  const float* bn1s  = (const float*)d_in[3];
  const float* bn1b  = (const float*)d_in[4];
  const float* ew2   = (const float*)d_in[5];
  const float* eb2   = (const float*)d_in[6];
  const float* bn2s  = (const float*)d_in[7];
  const float* bn2b  = (const float*)d_in[8];
  const float* ew3   = (const float*)d_in[9];
  const float* eb3   = (const float*)d_in[10];
  const float* bn3s  = (const float*)d_in[11];
  const float* bn3b  = (const float*)d_in[12];
  const float* ew4   = (const float*)d_in[13];
  const float* eb4   = (const float*)d_in[14];
  const float* embed = (const float*)d_in[15];
  const float* clsz  = (const float*)d_in[16];
  const float* dw1   = (const float*)d_in[17];
  const float* db1   = (const float*)d_in[18];
  const float* dbn1s = (const float*)d_in[19];
  const float* dbn1b = (const float*)d_in[20];
  const float* dw2   = (const float*)d_in[21];
  const float* db2   = (const float*)d_in[22];
  const float* dbn2s = (const float*)d_in[23];
  const float* dbn2b = (const float*)d_in[24];
  const float* dw3   = (const float*)d_in[25];
  const float* db3   = (const float*)d_in[26];
  const float* dbn3s = (const float*)d_in[27];
  const float* dbn3b = (const float*)d_in[28];
  const float* dw4   = (const float*)d_in[29];
  const float* db4   = (const float*)d_in[30];

  float* out = (float*)d_out;
  uint8_t* wsb = (uint8_t*)d_ws;

  float*  A1   = (float*)(wsb + WS_R1);
  float*  dist = (float*)(wsb + WS_R1);
  float*  D3f  = (float*)(wsb + WS_R1);      // f32 NHWC [32][128][128][64]
  float*  A2   = (float*)(wsb + WS_R2);
  ushort* D2h  = (ushort*)(wsb + WS_R2);
  ushort* D2l  = (ushort*)(wsb + WS_R2 + 17301504ull);
  float*  A3   = (float*)(wsb + WS_R3);
  ushort* D1h  = (ushort*)(wsb + WS_R3);
  ushort* D1l  = (ushort*)(wsb + WS_R3 + 8912896ull);
  float*  flat = (float*)(wsb + WS_FLAT);
  ushort* zqPh = (ushort*)(wsb + WS_ZQP);
  ushort* zqPl = (ushort*)(wsb + WS_ZQP + 1179648ull);

  ushort* wE2h = (ushort*)(wsb + WT_E2);
  ushort* wE2m = wE2h + 65536;  ushort* wE2l = wE2m + 65536;
  ushort* wE3h = (ushort*)(wsb + WT_E3);
  ushort* wE3m = wE3h + 131072; ushort* wE3l = wE3m + 131072;
  ushort* wE4h = (ushort*)(wsb + WT_E4);
  ushort* wE4m = wE4h + 131072; ushort* wE4l = wE4m + 131072;
  ushort* wD1h = (ushort*)(wsb + WT_D1);
  ushort* wD1l = wD1h + 131072;
  ushort* wD2h = (ushort*)(wsb + WT_D2);
  ushort* wD2l = wD2h + 131072;
  ushort* wD3h = (ushort*)(wsb + WT_D3);
  ushort* wD3l = wD3h + 65536;
  float*  w4   = (float*)(wsb + WS_W4);

  unsigned long long* rmp = (unsigned long long*)(wsb + ST_RMP);
  unsigned int* cnt = (unsigned int*)(wsb + ST_CNT);
  float* avgs   = (float*)(wsb + ST_AVGS);
  float* rowzi  = (float*)(wsb + ST_ROWZI);
  float* codesq = (float*)(wsb + ST_CODESQ);
  float* loss   = (float*)(wsb + ST_LOSS);

  dim3 B(256);

  k_init<<<32, B, 0, stream>>>(avgs, cnt, rmp, loss);

  // weight prep
  k_wsplit<<<256, B, 0, stream>>>(ew2, wE2h, wE2m, wE2l, 64, 64, 0, 1);
  k_wsplit<<<512, B, 0, stream>>>(ew3, wE3h, wE3m, wE3l, 128, 64, 0, 1);
  k_wsplit<<<512, B, 0, stream>>>(ew4, wE4h, wE4m, wE4l, 64, 128, 0, 1);
  k_wsplit<<<512, B, 0, stream>>>(dw1, wD1h, nullptr, wD1l, 128, 64, 1, 0);
  k_wsplit<<<512, B, 0, stream>>>(dw2, wD2h, nullptr, wD2l, 64, 128, 1, 0);
  k_wsplit<<<256, B, 0, stream>>>(dw3, wD3h, nullptr, wD3l, 64, 64, 1, 0);
  k_w4prep<<<4, B, 0, stream>>>(dw4, w4);

  // zero x-pad columns of padded fp32 encoder tensors + zqP
  k_zpad<<<1024, B, 0, stream>>>((unsigned*)A2, nullptr, 32*64, 66, 64);
  k_zpad<<<1024, B, 0, stream>>>((unsigned*)A3, nullptr, 32*32, 34, 128);
  k_zpad<<<128,  B, 0, stream>>>((unsigned*)zqPh, (unsigned*)zqPl, 32*16, 18, 32);

  // encoder
  enc_conv1<<<2048, B, 0, stream>>>(x, ew1, eb1, bn1s, bn1b, A1);
  enc_conv<64,64,64,64,128,128,false,false><<<2048, B, 0, stream>>>(
      A1, wE2h, wE2m, wE2l, eb2, bn2s, bn2b, A2, 1);
  enc_conv<64,128,32,32,64,64,true,false><<<1024, B, 0, stream>>>(
      A2, wE3h, wE3m, wE3l, eb3, bn3s, bn3b, A3, 2);
  enc_conv<128,64,16,16,32,32,true,true><<<128, B, 0, stream>>>(
      A3, wE4h, wE4m, wE4l, eb4, eb4, eb4, flat, 1);

  k_codesq<<<2048, B, 0, stream>>>(embed, codesq);

  // zero pad cols of decoder tensors (regions free now: A2/A3 consumed)
  k_zpad<<<512, B, 0, stream>>>((unsigned*)D1h, (unsigned*)D1l, 32*32, 34, 64);
  k_zpad<<<512, B, 0, stream>>>((unsigned*)D2h, (unsigned*)D2l, 32*64, 66, 32);

  // VQ in 2 row chunks (dist reuses dead A1 region)
  for (int chunk = 0; chunk < 2; chunk++){
    int rb = chunk * 4096;
    vq_gemm_mfma<<<2048, B, 0, stream>>>(flat, embed, codesq, dist, rmp, rb);
    vq_rowz<<<512, B, 0, stream>>>(dist, rmp, rowzi, rb);
    vq_colsum<<<256, B, 0, stream>>>(dist, rmp, rowzi, avgs, rb);
  }
  vq_post<<<2048, B, 0, stream>>>(flat, embed, rmp, out + O_CODES, out + O_ZQ,
                                  zqPh, zqPl, loss, cnt);

  // decoder
  dec_convT<64,128,16,16,true,0><<<1024, B, 0, stream>>>(
      zqPh, zqPl, wD1h, wD1l, db1, dbn1s, dbn1b, D1h, D1l, nullptr, 2);
  dec_convT<128,64,32,32,true,0><<<2048, B, 0, stream>>>(
      D1h, D1l, wD2h, wD2l, db2, dbn2s, dbn2b, D2h, D2l, nullptr, 1);
  dec_convT<64,64,64,64,false,1><<<8192, B, 0, stream>>>(
      D2h, D2l, wD3h, wD3l, db3, dbn3s, dbn3b, nullptr, nullptr, D3f, 1);
  dec_convT4<<<8192, B, 0, stream>>>(D3f, w4, db4, x, out + O_RECON, loss);

  k_final<<<1, B, 0, stream>>>(avgs, cnt, clsz, loss, out);
}